// Round 7
// baseline (4873.732 us; speedup 1.0000x reference)
//
#include <hip/hip_runtime.h>
#include <math.h>

// RipsLayer: dim-0 persistence of Rips filtration on 4096 points in R^64.
// Phase 1: dense distance matrix D (64 MiB, in d_ws).
// Phase 2: exact Prim replay, 1 workgroup, 16 waves (1024 threads x 4
// cols/lane, was 256 x 16):
//   - R4 evidence: trimming pre-barrier VALU didn't move duration -> the
//     critical path is exposed row-load latency + fixed exchange latency;
//     VALU is (partially) hidden under stalls. So: shrink every serial
//     segment that ISN'T hidden by going wider. Per-lane trees drop from
//     45 ops to ~12, fold 32->8; the post-load m2 segment shrinks by
//     ~200cy; exchange widens 4->16 keys (+~80cy resolve) - net win.
//   - DPP (row_shr/row_bcast) wave min-reduce + ballot index recovery
//     (blocked col ownership -> lowest lane == lowest col, exact ties)
//   - deferred m1 (from R4): next iter's mind-argmin key computed in the
//     row-load flight window via exact merge of this iter's argmins
//   - tree membership encoded as mind==INF (no mask bitfield)
//   - selection semantics bit-identical to the 4030us baseline.
// (Resubmitted unchanged: R5/R6 benches failed with GPUAcquisitionTimeout —
//  infrastructure, not kernel.)

#define N 4096
#define DF 64
#define INF __builtin_huge_valf()
#define INFBITS 0x7f800000u

// ---------------------------------------------------------------------------
// Phase 1: D[i][j] = sqrt(max(|x_i - x_j|^2, 1e-12)), diag = +inf.
// ---------------------------------------------------------------------------
__global__ __launch_bounds__(256) void build_d_kernel(const float* __restrict__ x,
                                                      float* __restrict__ D) {
    __shared__ float As[64][68];
    __shared__ float Bs[64][68];
    const int bi = blockIdx.y * 64;
    const int bj = blockIdx.x * 64;
    const int t = threadIdx.x;

#pragma unroll
    for (int g = 0; g < 4; ++g) {
        int idx = t + 256 * g;
        int row = idx >> 4;
        int k4 = (idx & 15) << 2;
        float4 va = *(const float4*)(x + (size_t)(bi + row) * DF + k4);
        float4 vb = *(const float4*)(x + (size_t)(bj + row) * DF + k4);
        *(float4*)(&As[row][k4]) = va;
        *(float4*)(&Bs[row][k4]) = vb;
    }
    __syncthreads();

    const int ti = (t >> 4) << 2;
    const int tj = (t & 15) << 2;

    float acc[4][4];
#pragma unroll
    for (int r = 0; r < 4; ++r)
#pragma unroll
        for (int c = 0; c < 4; ++c) acc[r][c] = 0.0f;

    for (int k = 0; k < 64; k += 4) {
        float4 a[4], b[4];
#pragma unroll
        for (int r = 0; r < 4; ++r) a[r] = *(const float4*)(&As[ti + r][k]);
#pragma unroll
        for (int c = 0; c < 4; ++c) b[c] = *(const float4*)(&Bs[tj + c][k]);
#pragma unroll
        for (int r = 0; r < 4; ++r)
#pragma unroll
            for (int c = 0; c < 4; ++c) {
                float d0 = a[r].x - b[c].x;
                float d1 = a[r].y - b[c].y;
                float d2 = a[r].z - b[c].z;
                float d3 = a[r].w - b[c].w;
                float s = acc[r][c];
                s = fmaf(d0, d0, s);
                s = fmaf(d1, d1, s);
                s = fmaf(d2, d2, s);
                s = fmaf(d3, d3, s);
                acc[r][c] = s;
            }
    }

#pragma unroll
    for (int r = 0; r < 4; ++r) {
        int i = bi + ti + r;
        float4 v;
        float* vp = &v.x;
#pragma unroll
        for (int c = 0; c < 4; ++c) {
            int j = bj + tj + c;
            vp[c] = (i == j) ? INF : sqrtf(fmaxf(acc[r][c], 1e-12f));
        }
        *(float4*)(D + (size_t)i * N + (bj + tj)) = v;
    }
}

// ---------------------------------------------------------------------------
// Barrier that publishes LDS (lgkmcnt) but leaves global loads in flight.
// ---------------------------------------------------------------------------
__device__ __forceinline__ void barrier_no_drain() {
    __asm__ __volatile__("s_waitcnt lgkmcnt(0)\n\ts_barrier" ::: "memory");
}

// ---------------------------------------------------------------------------
// Wave64 min via DPP: row_shr 1/2/4/8 then row_bcast 15/31; result in lane 63.
// update_dpp(old=INF,...) makes invalid source lanes contribute identity.
// ---------------------------------------------------------------------------
#define DPP_MIN_STEP(x, ctrl)                                                  \
    x = fminf(x, __int_as_float(__builtin_amdgcn_update_dpp(                   \
                     0x7f800000, __float_as_int(x), ctrl, 0xF, 0xF, false)))

__device__ __forceinline__ float wave_min_f32_l63(float x) {
    DPP_MIN_STEP(x, 0x111);  // row_shr:1
    DPP_MIN_STEP(x, 0x112);  // row_shr:2
    DPP_MIN_STEP(x, 0x114);  // row_shr:4
    DPP_MIN_STEP(x, 0x118);  // row_shr:8
    DPP_MIN_STEP(x, 0x142);  // row_bcast:15
    DPP_MIN_STEP(x, 0x143);  // row_bcast:31
    return x;                // lane 63 = wave min
}

// lv/lcol: this lane's local min value and its (lowest) column. Ownership is
// blocked (lane owns cols [4t,4t+4)), so among tied lanes the lowest lane
// holds the lowest column -> exact jnp.argmin first-index semantics.
__device__ __forceinline__ unsigned long long wave_argmin_key(float lv, int lcol) {
    float red = wave_min_f32_l63(lv);
    float wm = __int_as_float(__builtin_amdgcn_readlane(__float_as_int(red), 63));
    unsigned long long tied = __ballot(lv == wm);
    int src = __ffsll(tied) - 1;
    int wcol = __builtin_amdgcn_readlane(lcol, src);
    return ((unsigned long long)__float_as_uint(wm) << 32) | (unsigned)wcol;
}

// Local argmin over 4 values with exact lowest-index tie-break.
__device__ __forceinline__ void local_argmin4(const float* __restrict__ a,
                                              float& bv, int& bi) {
    float v0 = a[0], v1 = a[1], v2 = a[2], v3 = a[3];
    float m01 = v0;
    int i01 = 0;
    if (v1 < m01) { m01 = v1; i01 = 1; }   // strict: keep lower index on ties
    float m23 = v2;
    int i23 = 2;
    if (v3 < m23) { m23 = v3; i23 = 3; }
    bv = m01;
    bi = i01;
    if (m23 < bv) { bv = m23; bi = i23; }
}

// ---------------------------------------------------------------------------
// Phase 2. Invariant: mv[i] == INF  <=>  col (4t+i) is in the tree.
// 1024 threads = 16 waves; wave w owns cols [256w, 256w+256).
// ---------------------------------------------------------------------------
__global__ __launch_bounds__(1024) void prim_kernel(const float* __restrict__ D,
                                                    float* __restrict__ out) {
    __shared__ __align__(16) unsigned long long part[2][16];
    const int t = threadIdx.x;
    const int lane = t & 63;
    const int wv = t >> 6;

    float mv[4];  // mind, pinned INF at tree cols
    float rv[4];  // row of last-selected vertex (in flight across backedge)
    {
        float4 a = *(const float4*)(D + 4 * t);  // row 0; D[0][0]=INF
        mv[0] = a.x; mv[1] = a.y; mv[2] = a.z; mv[3] = a.w;
        rv[0] = a.x; rv[1] = a.y; rv[2] = a.z; rv[3] = a.w;
    }

    // Running per-lane argmin over mv and its wave-level key (m1, deferred).
    float bv1;
    int bi1;
    local_argmin4(mv, bv1, bi1);
    unsigned long long key1w = wave_argmin_key(bv1, 4 * t + bi1);

#pragma unroll 1
    for (int s = 1; s < N; ++s) {
        // ---- m2: argmin over the arrived row, tree cols masked to INF ----
        float mr[4];
#pragma unroll
        for (int i = 0; i < 4; ++i)
            mr[i] = (__float_as_uint(mv[i]) == INFBITS) ? INF : rv[i];
        float bv2;
        int bi2;
        local_argmin4(mr, bv2, bi2);
        unsigned long long key2 = wave_argmin_key(bv2, 4 * t + bi2);

        // ---- combine with the precomputed m1 key; exchange across waves ----
        unsigned long long kw = key1w < key2 ? key1w : key2;
        const int pb = s & 1;
        if (lane == 0) part[pb][wv] = kw;
        barrier_no_drain();

        const ulonglong2* pp = (const ulonglong2*)&part[pb][0];
        ulonglong2 q0 = pp[0], q1 = pp[1], q2 = pp[2], q3 = pp[3];
        ulonglong2 q4 = pp[4], q5 = pp[5], q6 = pp[6], q7 = pp[7];
        unsigned long long a0 = q0.x < q0.y ? q0.x : q0.y;
        unsigned long long a1 = q1.x < q1.y ? q1.x : q1.y;
        unsigned long long a2 = q2.x < q2.y ? q2.x : q2.y;
        unsigned long long a3 = q3.x < q3.y ? q3.x : q3.y;
        unsigned long long a4 = q4.x < q4.y ? q4.x : q4.y;
        unsigned long long a5 = q5.x < q5.y ? q5.x : q5.y;
        unsigned long long a6 = q6.x < q6.y ? q6.x : q6.y;
        unsigned long long a7 = q7.x < q7.y ? q7.x : q7.y;
        unsigned long long b0 = a0 < a1 ? a0 : a1;
        unsigned long long b1 = a2 < a3 ? a2 : a3;
        unsigned long long b2 = a4 < a5 ? a4 : a5;
        unsigned long long b3 = a6 < a7 ? a6 : a7;
        unsigned long long c0 = b0 < b1 ? b0 : b1;
        unsigned long long c1 = b2 < b3 ? b2 : b3;
        unsigned long long best = c0 < c1 ? c0 : c1;
        int j = __builtin_amdgcn_readfirstlane((int)(best & 0xffffffffULL));
        int dbits = __builtin_amdgcn_readfirstlane((int)(best >> 32));

        // ---- issue next row load immediately (consumed next iter in m2) ----
        float4 n0 = *(const float4*)(D + (size_t)(unsigned)j * N + 4 * t);

        if (t == 0) {
            out[2 * (s - 1)] = 0.0f;
            out[2 * (s - 1) + 1] = __uint_as_float((unsigned)dbits);
        }

        // ---- fold (mind = min(mind, maskedR)) + pin newly-added col j ----
        unsigned jl = (unsigned)j & 3u;
        unsigned jt = (unsigned)j >> 2;
        bool mine = ((unsigned)t == jt);
#pragma unroll
        for (int i = 0; i < 4; ++i) {
            float m = fminf(mv[i], mr[i]);
            mv[i] = (mine && ((unsigned)i == jl)) ? INF : m;
        }

        // ---- deferred m1 for next iter (runs inside the load window) ----
        // argmin(min(mv_old, mr)) == first-index merge of (bv1,bi1),(bv2,bi2);
        // only the lane whose pinned slot was that merged argmin recomputes.
        {
            bool oldwin = (bv1 < bv2) || (bv1 == bv2 && bi1 <= bi2);
            float bvm = oldwin ? bv1 : bv2;
            int bim = oldwin ? bi1 : bi2;
            if (mine && bim == (int)jl) {
                local_argmin4(mv, bvm, bim);  // post-pin recompute (1 lane)
            }
            bv1 = bvm;
            bi1 = bim;
            key1w = wave_argmin_key(bv1, 4 * t + bi1);
        }

        // ---- carry the new row ----
        rv[0] = n0.x; rv[1] = n0.y; rv[2] = n0.z; rv[3] = n0.w;
    }
}

// ---------------------------------------------------------------------------
extern "C" void kernel_launch(void* const* d_in, const int* in_sizes, int n_in,
                              void* d_out, int out_size, void* d_ws, size_t ws_size,
                              hipStream_t stream) {
    const float* x = (const float*)d_in[0];
    float* D = (float*)d_ws;     // requires ws_size >= N*N*4 = 64 MiB
    float* out = (float*)d_out;  // [N-1][2]: (birth=0, death)

    dim3 grid(N / 64, N / 64);
    build_d_kernel<<<grid, 256, 0, stream>>>(x, D);
    prim_kernel<<<1, 1024, 0, stream>>>(D, out);
}

// Round 8
// 4578.790 us; speedup vs baseline: 1.0644x; 1.0644x over previous
//
#include <hip/hip_runtime.h>
#include <math.h>

// RipsLayer: dim-0 persistence of Rips filtration on 4096 points in R^64.
// RESTRUCTURE (R8): dense-Prim (4030-4775us across 3 variants; floor ~4ms =
// one CU x 4095 serial iters x (16KB row from L3 + full reduce + barrier))
// is replaced by:
//   Phase 1: Boruvka MST on all 256 CUs, 12 fixed rounds. Distances are
//     recomputed from x (1 MiB, L2-resident) with the SAME per-pair fmaf
//     sequence as the old build_d (which matched the jax reference with
//     absmax 0.0), so MST edge weights are bitwise the reference deaths.
//     Per-component min edge via u64 key (wbits|v|col) + one atomicMin per
//     row per round. Merge: hook + 2-cycle resolve + LDS pointer jumping.
//   Phase 2: exact sparse Prim replay over the 4095 MST edges, ONE wave,
//     everything in LDS/registers -> no HBM in the serial loop. Per iter:
//     DPP wave argmin (identical tie semantics to jnp.argmin: per-lane
//     lowest-col, disjoint blocked lane ranges, ballot lowest-lane), winner
//     lane recomputes its 4-col group key + rescans 16 group keys, then
//     deg(j) tree-neighbor candidate updates. Prim-on-MST selects the same
//     vertex sequence as dense Prim (cut property; exact-fp-tie divergence
//     is measure-zero for this fixed Gaussian input).
// Dense D is never built: no 64 MiB write, ws usage ~115 KB.

#define N 4096
#define DF 64
#define INF __builtin_huge_valf()

// ---------------------------------------------------------------------------
// init: comp[v]=v, best[v]=~0, counters.
// ---------------------------------------------------------------------------
__global__ __launch_bounds__(256) void init_kernel(unsigned* comp,
                                                   unsigned long long* best,
                                                   unsigned* nedges, unsigned* done) {
    int i = blockIdx.x * 256 + threadIdx.x;
    if (i < N) {
        comp[i] = (unsigned)i;
        best[i] = ~0ULL;
    }
    if (i == 0) { *nedges = 0u; *done = 0u; }
}

// ---------------------------------------------------------------------------
// Boruvka min-edge: block b scans rows [16b,16b+16) x all 4096 cols.
// Per pair: d2 via the exact build_d fmaf sequence, w = sqrt(max(d2,1e-12)).
// key = (wbits<<24)|(row<<12)|col  (56 bits; weight-major, deterministic).
// One atomicMin per row into best[comp[row]].
// ---------------------------------------------------------------------------
__global__ __launch_bounds__(256) void minedge_kernel(const float* __restrict__ x,
                                                      const unsigned* __restrict__ comp,
                                                      unsigned long long* __restrict__ best,
                                                      const unsigned* __restrict__ done) {
    if (*done) return;
    __shared__ float xr[16][64];
    __shared__ float xc[64][68];  // +4 pad: breaks 16-way bank conflict on col reads
    __shared__ unsigned compr[16];
    __shared__ unsigned compc[64];
    __shared__ unsigned long long keybuf[256];
    const int t = threadIdx.x;
    const int b = blockIdx.x;
    const int r = t >> 4;
    const int rowv = b * 16 + r;

    {   // stage 16 rows of x (16x64 floats = 256 float4)
        int row = t >> 4, f4 = t & 15;
        *(float4*)&xr[row][f4 * 4] =
            *(const float4*)(x + (size_t)(b * 16 + row) * DF + f4 * 4);
        if (t < 16) compr[t] = comp[b * 16 + t];
    }
    __syncthreads();
    const unsigned cr = compr[r];
    unsigned long long mykey = ~0ULL;

    for (int tile = 0; tile < 64; ++tile) {
        {   // stage 64 cols of x (64x64 floats = 1024 float4; 4 per thread)
#pragma unroll
            for (int q = 0; q < 4; ++q) {
                int idx = t + 256 * q;
                int col = idx >> 4, k4 = (idx & 15) * 4;
                *(float4*)&xc[col][k4] =
                    *(const float4*)(x + (size_t)(tile * 64 + col) * DF + k4);
            }
            if (t < 64) compc[t] = comp[tile * 64 + t];
        }
        __syncthreads();
#pragma unroll
        for (int q = 0; q < 4; ++q) {
            int c = (t & 15) * 4 + q;
            unsigned cc = compc[c];
            if (cc != cr) {
                float s = 0.0f;
#pragma unroll
                for (int k = 0; k < 64; k += 4) {
                    float4 a = *(const float4*)&xr[r][k];
                    float4 bb = *(const float4*)&xc[c][k];
                    float d0 = a.x - bb.x;
                    float d1 = a.y - bb.y;
                    float d2 = a.z - bb.z;
                    float d3 = a.w - bb.w;
                    s = fmaf(d0, d0, s);
                    s = fmaf(d1, d1, s);
                    s = fmaf(d2, d2, s);
                    s = fmaf(d3, d3, s);
                }
                float w = sqrtf(fmaxf(s, 1e-12f));
                unsigned long long key =
                    ((unsigned long long)__float_as_uint(w) << 24) |
                    ((unsigned long long)(unsigned)rowv << 12) |
                    (unsigned)(tile * 64 + c);
                mykey = key < mykey ? key : mykey;
            }
        }
        __syncthreads();
    }
    keybuf[t] = mykey;
    __syncthreads();
    if (t < 16) {
        unsigned long long k = ~0ULL;
#pragma unroll
        for (int i = 0; i < 16; ++i) {
            unsigned long long v2 = keybuf[t * 16 + i];
            k = v2 < k ? v2 : k;
        }
        if (k != ~0ULL) atomicMin(&best[compr[t]], k);
    }
}

// ---------------------------------------------------------------------------
// Boruvka merge: hook roots along best edges, resolve 2-cycles (unique keys
// => only 2-cycles possible), emit one MST edge per dying root, pointer-jump
// comp to new roots in LDS, reset best, set done when one component remains.
// ---------------------------------------------------------------------------
__global__ __launch_bounds__(256) void merge_kernel(unsigned* comp,
                                                    unsigned long long* best,
                                                    unsigned long long* edges,
                                                    unsigned* nedges, unsigned* done) {
    if (*done) return;
    __shared__ unsigned cl[N];
    __shared__ unsigned np[N];
    __shared__ unsigned cnt;
    const int t = threadIdx.x;
    for (int v = t; v < N; v += 256) cl[v] = comp[v];
    __syncthreads();
    for (int v = t; v < N; v += 256) {
        unsigned p;
        if (cl[v] == (unsigned)v) {
            unsigned long long k = best[v];
            p = (k != ~0ULL) ? cl[(unsigned)(k & 0xFFFu)] : (unsigned)v;
        } else {
            p = cl[v];
        }
        np[v] = p;
    }
    __syncthreads();
    // cycle resolve + emit (roots only). Mutual pair shares one edge; the
    // smaller root survives, the larger emits. Writes/reads race benignly:
    // both interleavings give the same outcome (analyzed: only the mutual
    // partner can flip np[p]->p, and both orders classify consistently).
    for (int v = t; v < N; v += 256) {
        if (cl[v] == (unsigned)v) {
            unsigned p = np[v];
            if (p != (unsigned)v) {
                bool mutual = (np[p] == (unsigned)v);
                if (mutual && (unsigned)v < p) {
                    np[v] = (unsigned)v;  // survives as root, no emit
                } else {
                    unsigned idx = atomicAdd(nedges, 1u);
                    edges[idx] = best[v];
                }
            }
        }
    }
    __syncthreads();
    for (int it = 0; it < 12; ++it) {
        for (int v = t; v < N; v += 256) np[v] = np[np[v]];
        __syncthreads();
    }
    if (t == 0) cnt = 0;
    __syncthreads();
    unsigned local = 0;
    for (int v = t; v < N; v += 256) {
        comp[v] = np[v];
        best[v] = ~0ULL;
        if (np[v] == (unsigned)v) ++local;
    }
    atomicAdd(&cnt, local);
    __syncthreads();
    if (t == 0 && cnt == 1u) *done = 1u;
}

// ---------------------------------------------------------------------------
// Wave64 min via DPP + ballot argmin (identical machinery/tie semantics to
// the verified dense kernel; lane ranges blocked & disjoint).
// ---------------------------------------------------------------------------
#define DPP_MIN_STEP(x, ctrl)                                                  \
    x = fminf(x, __int_as_float(__builtin_amdgcn_update_dpp(                   \
                     0x7f800000, __float_as_int(x), ctrl, 0xF, 0xF, false)))

__device__ __forceinline__ float wave_min_f32_l63(float x) {
    DPP_MIN_STEP(x, 0x111);
    DPP_MIN_STEP(x, 0x112);
    DPP_MIN_STEP(x, 0x114);
    DPP_MIN_STEP(x, 0x118);
    DPP_MIN_STEP(x, 0x142);
    DPP_MIN_STEP(x, 0x143);
    return x;
}

__device__ __forceinline__ unsigned long long wave_argmin_key(float lv, int lcol) {
    float red = wave_min_f32_l63(lv);
    float wm = __int_as_float(__builtin_amdgcn_readlane(__float_as_int(red), 63));
    unsigned long long tied = __ballot(lv == wm);
    int src = __ffsll(tied) - 1;
    int wcol = __builtin_amdgcn_readlane(lcol, src);
    return ((unsigned long long)__float_as_uint(wm) << 32) | (unsigned)wcol;
}

// ---------------------------------------------------------------------------
// Sparse Prim replay on the MST. Build adjacency in LDS (256 threads), then
// wave 0 replays 4095 selections entirely from LDS/registers.
// Lane L owns cols [64L, 64L+64); per-lane running (lv,lc); per-lane 16
// group keys ((wbits<<32)|col) in LDS for O(16) winner-lane rescans.
// ---------------------------------------------------------------------------
__global__ __launch_bounds__(256) void replay_kernel(
        const unsigned long long* __restrict__ edges,
        const unsigned* __restrict__ nedges, float* __restrict__ out) {
    __shared__ unsigned cnt[N];          // counts, then insertion pointers
    __shared__ unsigned off[N + 1];
    __shared__ unsigned short adjc[2 * (N - 1) + 2];
    __shared__ unsigned adjw[2 * (N - 1) + 2];
    __shared__ float mind[N];
    __shared__ unsigned long long gkey[64 * 16];
    __shared__ unsigned csum[256];
    const int t = threadIdx.x;
    const unsigned ne = *nedges;

    for (int v = t; v < N; v += 256) { cnt[v] = 0u; mind[v] = INF; }
    for (int g = t; g < 64 * 16; g += 256) gkey[g] = ~0ULL;
    for (int k = t; k < N - 1; k += 256) out[2 * k] = 0.0f;  // births
    __syncthreads();
    for (int e = t; e < (int)ne; e += 256) {
        unsigned long long k = edges[e];
        unsigned v = (unsigned)(k >> 12) & 0xFFFu;
        unsigned c = (unsigned)k & 0xFFFu;
        atomicAdd(&cnt[v], 1u);
        atomicAdd(&cnt[c], 1u);
    }
    __syncthreads();
    {   // exclusive prefix sum cnt -> off
        unsigned s = 0;
        int base = t * 16;
#pragma unroll
        for (int i = 0; i < 16; ++i) {
            unsigned d = cnt[base + i];
            off[base + i] = s;
            s += d;
        }
        csum[t] = s;
    }
    __syncthreads();
    if (t == 0) {
        unsigned run = 0;
        for (int i = 0; i < 256; ++i) {
            unsigned v2 = csum[i];
            csum[i] = run;
            run += v2;
        }
        off[N] = run;
    }
    __syncthreads();
    {
        int base = t * 16;
        unsigned add = csum[t];
#pragma unroll
        for (int i = 0; i < 16; ++i) {
            unsigned o = off[base + i] + add;
            off[base + i] = o;
            cnt[base + i] = o;  // insertion pointer
        }
    }
    __syncthreads();
    for (int e = t; e < (int)ne; e += 256) {
        unsigned long long k = edges[e];
        unsigned v = (unsigned)(k >> 12) & 0xFFFu;
        unsigned c = (unsigned)k & 0xFFFu;
        unsigned wb = (unsigned)(k >> 24);
        unsigned p1 = atomicAdd(&cnt[v], 1u);
        adjc[p1] = (unsigned short)c;
        adjw[p1] = wb;
        unsigned p2 = atomicAdd(&cnt[c], 1u);
        adjc[p2] = (unsigned short)v;
        adjw[p2] = wb;
    }
    __syncthreads();
    if (t >= 64) return;  // wave 0 only from here; no further __syncthreads

    const int lane = t;
    unsigned long long intree = (lane == 0) ? 1ULL : 0ULL;  // vertex 0 seeded
    float lv = INF;
    int lc = 0;

    {   // push adjacency of vertex 0
        unsigned o0 = off[0], d0 = off[1] - off[0];
        for (unsigned e = 0; e < d0; ++e) {
            unsigned c = adjc[o0 + e];
            unsigned wb = adjw[o0 + e];
            if ((int)(c >> 6) == lane) {
                float w = __uint_as_float(wb);
                mind[c] = w;
                int g = (int)((c & 63u) >> 2);
                unsigned long long k2 = ((unsigned long long)wb << 32) | c;
                unsigned long long old = gkey[lane * 16 + g];
                if (k2 < old) gkey[lane * 16 + g] = k2;
                if (w < lv || (w == lv && (int)c < lc)) { lv = w; lc = (int)c; }
            }
        }
    }

#pragma unroll 1
    for (int s = 1; s < N; ++s) {
        unsigned long long key = wave_argmin_key(lv, lc);
        int j = (int)(key & 0xFFFFFFFFULL);
        unsigned wmb = (unsigned)(key >> 32);
        if (lane == 0) out[2 * (s - 1) + 1] = __uint_as_float(wmb);

        if ((j >> 6) == lane) {  // winner lane: remove j, exact rescan
            intree |= 1ULL << (j & 63);
            mind[j] = INF;
            int g = (j & 63) >> 2;
            int cbase = (lane << 6) | (g << 2);
            float4 mm = *(const float4*)&mind[cbase];
            unsigned long long k0 =
                ((unsigned long long)__float_as_uint(mm.x) << 32) | (unsigned)(cbase + 0);
            unsigned long long k1 =
                ((unsigned long long)__float_as_uint(mm.y) << 32) | (unsigned)(cbase + 1);
            unsigned long long k2_ =
                ((unsigned long long)__float_as_uint(mm.z) << 32) | (unsigned)(cbase + 2);
            unsigned long long k3 =
                ((unsigned long long)__float_as_uint(mm.w) << 32) | (unsigned)(cbase + 3);
            unsigned long long ga = k0 < k1 ? k0 : k1;
            unsigned long long gb = k2_ < k3 ? k2_ : k3;
            gkey[lane * 16 + g] = ga < gb ? ga : gb;
            unsigned long long m = ~0ULL;
#pragma unroll
            for (int i = 0; i < 16; ++i) {
                unsigned long long v2 = gkey[lane * 16 + i];
                m = v2 < m ? v2 : m;
            }
            if (m == ~0ULL) {
                lv = INF;
                lc = 0;
            } else {
                lv = __uint_as_float((unsigned)(m >> 32));  // INF-keyed ok
                lc = (int)(m & 0xFFFu);
            }
        }

        // push adjacency of j (wave-uniform loop; owner lane applies)
        unsigned oj = off[j], dj = off[j + 1] - off[j];
        for (unsigned e = 0; e < dj; ++e) {
            unsigned c = adjc[oj + e];
            unsigned wb = adjw[oj + e];
            if ((int)(c >> 6) == lane && !((intree >> (c & 63u)) & 1ULL)) {
                float w = __uint_as_float(wb);
                if (w < mind[c]) {
                    mind[c] = w;
                    int g = (int)((c & 63u) >> 2);
                    unsigned long long k2 = ((unsigned long long)wb << 32) | c;
                    unsigned long long old = gkey[lane * 16 + g];
                    if (k2 < old) gkey[lane * 16 + g] = k2;
                    if (w < lv || (w == lv && (int)c < lc)) { lv = w; lc = (int)c; }
                }
            }
        }
    }
}

// ---------------------------------------------------------------------------
extern "C" void kernel_launch(void* const* d_in, const int* in_sizes, int n_in,
                              void* d_out, int out_size, void* d_ws, size_t ws_size,
                              hipStream_t stream) {
    const float* x = (const float*)d_in[0];
    unsigned char* ws = (unsigned char*)d_ws;  // uses ~115 KB total
    unsigned* comp = (unsigned*)ws;                                  // 16 KB
    unsigned long long* best = (unsigned long long*)(ws + 16384);    // 32 KB
    unsigned long long* edges = (unsigned long long*)(ws + 49152);   // 32 KB
    unsigned* nedges = (unsigned*)(ws + 81920);
    unsigned* done = (unsigned*)(ws + 81984);
    float* out = (float*)d_out;  // [N-1][2]: (birth=0, death)

    init_kernel<<<16, 256, 0, stream>>>(comp, best, nedges, done);
    for (int r = 0; r < 12; ++r) {  // 4096 -> 1 guaranteed in <=12 halvings
        minedge_kernel<<<256, 256, 0, stream>>>(x, comp, best, done);
        merge_kernel<<<1, 256, 0, stream>>>(comp, best, edges, nedges, done);
    }
    replay_kernel<<<1, 256, 0, stream>>>(edges, nedges, out);
}

// Round 9
// 3914.782 us; speedup vs baseline: 1.2450x; 1.1696x over previous
//
#include <hip/hip_runtime.h>
#include <math.h>

// RipsLayer: dim-0 persistence of Rips filtration on 4096 points in R^64.
// Boruvka MST (all CUs) + single-wave sparse Prim replay (no HBM in loop).
// R9: replay rebuilt around tree structure: frontier keys are SET-ONCE
// (at most one neighbor of a non-tree vertex can be in the tree), so the
// push needs no mind read-compare. Inline-2 adjacency (ds_read_b128 at
// j*16, no CSR indirection), deg+tailbase packed in one word, groups of 8
// with register replace on rescan. minedge lane->col remap fixes the
// 8-way xc bank conflict (4.6e7 -> ~0).

#define N 4096
#define DF 64
#define INF __builtin_huge_valf()

// ---------------------------------------------------------------------------
__global__ __launch_bounds__(256) void init_kernel(unsigned* comp,
                                                   unsigned long long* best,
                                                   unsigned* nedges, unsigned* done) {
    int i = blockIdx.x * 256 + threadIdx.x;
    if (i < N) {
        comp[i] = (unsigned)i;
        best[i] = ~0ULL;
    }
    if (i == 0) { *nedges = 0u; *done = 0u; }
}

// ---------------------------------------------------------------------------
// Boruvka min-edge: block b scans rows [16b,16b+16) x all 4096 cols.
// Exact build_d fmaf sequence -> w bitwise-identical to reference deaths.
// key = (wbits<<24)|(row<<12)|col.
// ---------------------------------------------------------------------------
__global__ __launch_bounds__(256) void minedge_kernel(const float* __restrict__ x,
                                                      const unsigned* __restrict__ comp,
                                                      unsigned long long* __restrict__ best,
                                                      const unsigned* __restrict__ done) {
    if (*done) return;
    __shared__ float xr[16][64];
    __shared__ float xc[64][68];
    __shared__ unsigned compr[16];
    __shared__ unsigned compc[64];
    __shared__ unsigned long long keybuf[256];
    const int t = threadIdx.x;
    const int b = blockIdx.x;
    const int r = t >> 4;
    const int rowv = b * 16 + r;

    {
        int row = t >> 4, f4 = t & 15;
        *(float4*)&xr[row][f4 * 4] =
            *(const float4*)(x + (size_t)(b * 16 + row) * DF + f4 * 4);
        if (t < 16) compr[t] = comp[b * 16 + t];
    }
    __syncthreads();
    const unsigned cr = compr[r];
    unsigned long long mykey = ~0ULL;

    for (int tile = 0; tile < 64; ++tile) {
        {
#pragma unroll
            for (int q = 0; q < 4; ++q) {
                int idx = t + 256 * q;
                int col = idx >> 4, k4 = (idx & 15) * 4;
                *(float4*)&xc[col][k4] =
                    *(const float4*)(x + (size_t)(tile * 64 + col) * DF + k4);
            }
            if (t < 64) compc[t] = comp[tile * 64 + t];
        }
        __syncthreads();
#pragma unroll
        for (int q = 0; q < 4; ++q) {
            int c = (t & 15) + 16 * q;  // consecutive lanes -> consecutive cols
            unsigned cc = compc[c];
            if (cc != cr) {
                float s = 0.0f;
#pragma unroll
                for (int k = 0; k < 64; k += 4) {
                    float4 a = *(const float4*)&xr[r][k];
                    float4 bb = *(const float4*)&xc[c][k];
                    float d0 = a.x - bb.x;
                    float d1 = a.y - bb.y;
                    float d2 = a.z - bb.z;
                    float d3 = a.w - bb.w;
                    s = fmaf(d0, d0, s);
                    s = fmaf(d1, d1, s);
                    s = fmaf(d2, d2, s);
                    s = fmaf(d3, d3, s);
                }
                float w = sqrtf(fmaxf(s, 1e-12f));
                unsigned long long key =
                    ((unsigned long long)__float_as_uint(w) << 24) |
                    ((unsigned long long)(unsigned)rowv << 12) |
                    (unsigned)(tile * 64 + c);
                mykey = key < mykey ? key : mykey;
            }
        }
        __syncthreads();
    }
    keybuf[t] = mykey;
    __syncthreads();
    if (t < 16) {
        unsigned long long k = ~0ULL;
#pragma unroll
        for (int i = 0; i < 16; ++i) {
            unsigned long long v2 = keybuf[t * 16 + i];
            k = v2 < k ? v2 : k;
        }
        if (k != ~0ULL) atomicMin(&best[compr[t]], k);
    }
}

// ---------------------------------------------------------------------------
__global__ __launch_bounds__(256) void merge_kernel(unsigned* comp,
                                                    unsigned long long* best,
                                                    unsigned long long* edges,
                                                    unsigned* nedges, unsigned* done) {
    if (*done) return;
    __shared__ unsigned cl[N];
    __shared__ unsigned np[N];
    __shared__ unsigned cnt;
    const int t = threadIdx.x;
    for (int v = t; v < N; v += 256) cl[v] = comp[v];
    __syncthreads();
    for (int v = t; v < N; v += 256) {
        unsigned p;
        if (cl[v] == (unsigned)v) {
            unsigned long long k = best[v];
            p = (k != ~0ULL) ? cl[(unsigned)(k & 0xFFFu)] : (unsigned)v;
        } else {
            p = cl[v];
        }
        np[v] = p;
    }
    __syncthreads();
    for (int v = t; v < N; v += 256) {
        if (cl[v] == (unsigned)v) {
            unsigned p = np[v];
            if (p != (unsigned)v) {
                bool mutual = (np[p] == (unsigned)v);
                if (mutual && (unsigned)v < p) {
                    np[v] = (unsigned)v;
                } else {
                    unsigned idx = atomicAdd(nedges, 1u);
                    edges[idx] = best[v];
                }
            }
        }
    }
    __syncthreads();
    for (int it = 0; it < 12; ++it) {
        for (int v = t; v < N; v += 256) np[v] = np[np[v]];
        __syncthreads();
    }
    if (t == 0) cnt = 0;
    __syncthreads();
    unsigned local = 0;
    for (int v = t; v < N; v += 256) {
        comp[v] = np[v];
        best[v] = ~0ULL;
        if (np[v] == (unsigned)v) ++local;
    }
    atomicAdd(&cnt, local);
    __syncthreads();
    if (t == 0 && cnt == 1u) *done = 1u;
}

// ---------------------------------------------------------------------------
#define DPP_MIN_STEP(x, ctrl)                                                  \
    x = fminf(x, __int_as_float(__builtin_amdgcn_update_dpp(                   \
                     0x7f800000, __float_as_int(x), ctrl, 0xF, 0xF, false)))

__device__ __forceinline__ float wave_min_f32_l63(float x) {
    DPP_MIN_STEP(x, 0x111);
    DPP_MIN_STEP(x, 0x112);
    DPP_MIN_STEP(x, 0x114);
    DPP_MIN_STEP(x, 0x118);
    DPP_MIN_STEP(x, 0x142);
    DPP_MIN_STEP(x, 0x143);
    return x;
}

__device__ __forceinline__ unsigned long long wave_argmin_key(float lv, int lcol) {
    float red = wave_min_f32_l63(lv);
    float wm = __int_as_float(__builtin_amdgcn_readlane(__float_as_int(red), 63));
    unsigned long long tied = __ballot(lv == wm);
    int src = __ffsll(tied) - 1;
    int wcol = __builtin_amdgcn_readlane(lcol, src);
    return ((unsigned long long)__float_as_uint(wm) << 32) | (unsigned)wcol;
}

__device__ __forceinline__ unsigned long long umin64(unsigned long long a,
                                                     unsigned long long b) {
    return a < b ? a : b;
}

// ---------------------------------------------------------------------------
// Sparse Prim replay. Lane L owns cols [64L,64L+64) in 8 groups of 8.
// Set-once frontier keys; inline-2 adjacency + rare tail.
// ---------------------------------------------------------------------------
__global__ __launch_bounds__(256) void replay_kernel(
        const unsigned long long* __restrict__ edges,
        const unsigned* __restrict__ nedges, float* __restrict__ out) {
    __shared__ unsigned tidx[N];              // (tailbase<<8) | fill/deg
    __shared__ float mind[N];                 // set-once keys; INF = not frontier
    __shared__ unsigned long long gk[64 * 8]; // per-lane 8 group keys
    __shared__ ulonglong2 in2[N];             // first 2 adjacency entries
    __shared__ unsigned long long tail[4094]; // entries beyond 2 (exact bound)
    __shared__ unsigned csum[256];
    const int t = threadIdx.x;
    const unsigned ne = *nedges;

    for (int v = t; v < N; v += 256) { tidx[v] = 0u; mind[v] = INF; }
    for (int g = t; g < 64 * 8; g += 256) gk[g] = ~0ULL;
    for (int k = t; k < N - 1; k += 256) out[2 * k] = 0.0f;  // births
    __syncthreads();
    for (int e = t; e < (int)ne; e += 256) {
        unsigned long long k = edges[e];
        atomicAdd(&tidx[(unsigned)(k >> 12) & 0xFFFu], 1u);
        atomicAdd(&tidx[(unsigned)k & 0xFFFu], 1u);
    }
    __syncthreads();
    {   // prefix over max(deg-2,0); rewrite tidx = tailbase<<8 (fill=0)
        unsigned s = 0;
        int base = t * 16;
        unsigned loc[16], dsv[16];
#pragma unroll
        for (int i = 0; i < 16; ++i) {
            unsigned d = tidx[base + i];
            dsv[i] = d;
            loc[i] = s;
            s += (d > 2u) ? (d - 2u) : 0u;
        }
        csum[t] = s;
        __syncthreads();
        if (t == 0) {
            unsigned run = 0;
            for (int i = 0; i < 256; ++i) {
                unsigned v2 = csum[i];
                csum[i] = run;
                run += v2;
            }
        }
        __syncthreads();
        unsigned add = csum[t];
        (void)dsv;
#pragma unroll
        for (int i = 0; i < 16; ++i) tidx[base + i] = (loc[i] + add) << 8;
    }
    __syncthreads();
    for (int e = t; e < (int)ne; e += 256) {
        unsigned long long k = edges[e];
        unsigned v = (unsigned)(k >> 12) & 0xFFFu;
        unsigned c = (unsigned)k & 0xFFFu;
        unsigned long long wb = k >> 24;
        {
            unsigned old = atomicAdd(&tidx[v], 1u);
            unsigned slot = old & 0xFFu, tb = old >> 8;
            unsigned long long entry = (wb << 32) | c;
            if (slot < 2u) ((unsigned long long*)&in2[v])[slot] = entry;
            else tail[tb + slot - 2u] = entry;
        }
        {
            unsigned old = atomicAdd(&tidx[c], 1u);
            unsigned slot = old & 0xFFu, tb = old >> 8;
            unsigned long long entry = (wb << 32) | v;
            if (slot < 2u) ((unsigned long long*)&in2[c])[slot] = entry;
            else tail[tb + slot - 2u] = entry;
        }
    }
    __syncthreads();
    if (t >= 64) return;  // wave 0 only; no further __syncthreads

    const int lane = t;
    unsigned long long intree = (lane == 0) ? 1ULL : 0ULL;
    float lv = INF;
    int lc = 0;

    auto PROC = [&](unsigned long long e) {
        unsigned c = (unsigned)e & 0xFFFu;
        if ((int)(c >> 6) == lane && !((intree >> (c & 63u)) & 1ULL)) {
            unsigned wbu = (unsigned)(e >> 32);
            float w = __uint_as_float(wbu);
            mind[c] = w;  // set-once (tree property: no frontier re-push)
            int g = (int)((c & 63u) >> 3);
            unsigned long long key = ((unsigned long long)wbu << 32) | c;
            unsigned long long old = gk[lane * 8 + g];
            if (key < old) gk[lane * 8 + g] = key;
            if (w < lv || (w == lv && (int)c < lc)) { lv = w; lc = (int)c; }
        }
    };

    {   // seed: push adjacency of vertex 0
        ulonglong2 e01 = in2[0];
        unsigned ti0 = tidx[0];
        unsigned dj = ti0 & 0xFFu;
        PROC(e01.x);
        if (dj > 1u) PROC(e01.y);
        if (dj > 2u) {
            unsigned tb = ti0 >> 8;
            for (unsigned e2 = 0; e2 < dj - 2u; ++e2) PROC(tail[tb + e2]);
        }
    }

#pragma unroll 1
    for (int s = 1; s < N; ++s) {
        unsigned long long key = wave_argmin_key(lv, lc);
        int j = (int)(key & 0xFFFFFFFFULL);
        unsigned wmb = (unsigned)(key >> 32);

        // issue j-dependent loads early (fly under the winner branch)
        ulonglong2 e01 = in2[j];
        unsigned tij = tidx[j];

        if (lane == 0) out[2 * (s - 1) + 1] = __uint_as_float(wmb);

        if ((j >> 6) == lane) {  // winner: remove j, rescan own 64 cols
            intree |= 1ULL << (j & 63);
            mind[j] = INF;
            int g = (j & 63) >> 3;
            int cb = (lane << 6) | (g << 3);
            float4 ma = *(const float4*)&mind[cb];
            float4 mb = *(const float4*)&mind[cb + 4];
            ulonglong2 G0 = *(const ulonglong2*)&gk[lane * 8 + 0];
            ulonglong2 G1 = *(const ulonglong2*)&gk[lane * 8 + 2];
            ulonglong2 G2 = *(const ulonglong2*)&gk[lane * 8 + 4];
            ulonglong2 G3 = *(const ulonglong2*)&gk[lane * 8 + 6];
            unsigned long long k0 =
                ((unsigned long long)__float_as_uint(ma.x) << 32) | (unsigned)(cb + 0);
            unsigned long long k1 =
                ((unsigned long long)__float_as_uint(ma.y) << 32) | (unsigned)(cb + 1);
            unsigned long long k2 =
                ((unsigned long long)__float_as_uint(ma.z) << 32) | (unsigned)(cb + 2);
            unsigned long long k3 =
                ((unsigned long long)__float_as_uint(ma.w) << 32) | (unsigned)(cb + 3);
            unsigned long long k4 =
                ((unsigned long long)__float_as_uint(mb.x) << 32) | (unsigned)(cb + 4);
            unsigned long long k5 =
                ((unsigned long long)__float_as_uint(mb.y) << 32) | (unsigned)(cb + 5);
            unsigned long long k6 =
                ((unsigned long long)__float_as_uint(mb.z) << 32) | (unsigned)(cb + 6);
            unsigned long long k7 =
                ((unsigned long long)__float_as_uint(mb.w) << 32) | (unsigned)(cb + 7);
            unsigned long long ng = umin64(umin64(umin64(k0, k1), umin64(k2, k3)),
                                           umin64(umin64(k4, k5), umin64(k6, k7)));
            gk[lane * 8 + g] = ng;
            unsigned long long q0 = (g == 0) ? ng : G0.x;
            unsigned long long q1 = (g == 1) ? ng : G0.y;
            unsigned long long q2 = (g == 2) ? ng : G1.x;
            unsigned long long q3 = (g == 3) ? ng : G1.y;
            unsigned long long q4 = (g == 4) ? ng : G2.x;
            unsigned long long q5 = (g == 5) ? ng : G2.y;
            unsigned long long q6 = (g == 6) ? ng : G3.x;
            unsigned long long q7 = (g == 7) ? ng : G3.y;
            unsigned long long m = umin64(umin64(umin64(q0, q1), umin64(q2, q3)),
                                          umin64(umin64(q4, q5), umin64(q6, q7)));
            lv = __uint_as_float((unsigned)(m >> 32));  // INF-key if empty
            lc = (int)(m & 0xFFFu);
        }

        // push adjacency of j (set-once inserts, owner-lane applies)
        unsigned dj = tij & 0xFFu;
        PROC(e01.x);
        if (dj > 1u) PROC(e01.y);
        if (dj > 2u) {
            unsigned tb = tij >> 8;
#pragma unroll 1
            for (unsigned e2 = 0; e2 < dj - 2u; ++e2) PROC(tail[tb + e2]);
        }
    }
}

// ---------------------------------------------------------------------------
extern "C" void kernel_launch(void* const* d_in, const int* in_sizes, int n_in,
                              void* d_out, int out_size, void* d_ws, size_t ws_size,
                              hipStream_t stream) {
    const float* x = (const float*)d_in[0];
    unsigned char* ws = (unsigned char*)d_ws;
    unsigned* comp = (unsigned*)ws;                                  // 16 KB
    unsigned long long* best = (unsigned long long*)(ws + 16384);    // 32 KB
    unsigned long long* edges = (unsigned long long*)(ws + 49152);   // 32 KB
    unsigned* nedges = (unsigned*)(ws + 81920);
    unsigned* done = (unsigned*)(ws + 81984);
    float* out = (float*)d_out;  // [N-1][2]: (birth=0, death)

    init_kernel<<<16, 256, 0, stream>>>(comp, best, nedges, done);
    for (int r = 0; r < 12; ++r) {
        minedge_kernel<<<256, 256, 0, stream>>>(x, comp, best, done);
        merge_kernel<<<1, 256, 0, stream>>>(comp, best, edges, nedges, done);
    }
    replay_kernel<<<1, 256, 0, stream>>>(edges, nedges, out);
}

// Round 10
// 2259.899 us; speedup vs baseline: 2.1566x; 1.7323x over previous
//
#include <hip/hip_runtime.h>
#include <math.h>

// RipsLayer: dim-0 persistence of Rips filtration on 4096 points in R^64.
// Boruvka MST (all CUs) + replay WITHOUT serial Prim (R10):
//   Theory: root MST at 0; key(v) = w(v,parent). Prim pop order ==
//   "process v by increasing key; append chain(v) to chain(find(parent))".
//   Final pop position(v) = sum of chain-offsets along the merge tree.
//   => replay becomes: BFS rooting (parallel) + bitonic key sort (parallel)
//      + tiny serial DSU chain-merge (O(1) LDS ops/step, no wave-argmin,
//      no divergence) + pointer-doubling position sum (parallel) + scatter.
//   Verified by hand on 6 tree cases incl. chain-into-chain merges.
//   Assumes distinct edge weights (a.s. for Gaussian input; same
//   genericity assumption R8/R9 passed absmax=0 on).

#define N 4096
#define DF 64
#define INF __builtin_huge_valf()

// ---------------------------------------------------------------------------
__global__ __launch_bounds__(256) void init_kernel(unsigned* comp,
                                                   unsigned long long* best,
                                                   unsigned* nedges, unsigned* done) {
    int i = blockIdx.x * 256 + threadIdx.x;
    if (i < N) {
        comp[i] = (unsigned)i;
        best[i] = ~0ULL;
    }
    if (i == 0) { *nedges = 0u; *done = 0u; }
}

// ---------------------------------------------------------------------------
// Boruvka min-edge: block b scans rows [16b,16b+16) x all 4096 cols.
// Exact build_d fmaf sequence -> w bitwise-identical to reference deaths.
// key = (wbits<<24)|(row<<12)|col.
// ---------------------------------------------------------------------------
__global__ __launch_bounds__(256) void minedge_kernel(const float* __restrict__ x,
                                                      const unsigned* __restrict__ comp,
                                                      unsigned long long* __restrict__ best,
                                                      const unsigned* __restrict__ done) {
    if (*done) return;
    __shared__ float xr[16][64];
    __shared__ float xc[64][68];
    __shared__ unsigned compr[16];
    __shared__ unsigned compc[64];
    __shared__ unsigned long long keybuf[256];
    const int t = threadIdx.x;
    const int b = blockIdx.x;
    const int r = t >> 4;
    const int rowv = b * 16 + r;

    {
        int row = t >> 4, f4 = t & 15;
        *(float4*)&xr[row][f4 * 4] =
            *(const float4*)(x + (size_t)(b * 16 + row) * DF + f4 * 4);
        if (t < 16) compr[t] = comp[b * 16 + t];
    }
    __syncthreads();
    const unsigned cr = compr[r];
    unsigned long long mykey = ~0ULL;

    for (int tile = 0; tile < 64; ++tile) {
        {
#pragma unroll
            for (int q = 0; q < 4; ++q) {
                int idx = t + 256 * q;
                int col = idx >> 4, k4 = (idx & 15) * 4;
                *(float4*)&xc[col][k4] =
                    *(const float4*)(x + (size_t)(tile * 64 + col) * DF + k4);
            }
            if (t < 64) compc[t] = comp[tile * 64 + t];
        }
        __syncthreads();
#pragma unroll
        for (int q = 0; q < 4; ++q) {
            int c = (t & 15) + 16 * q;  // consecutive lanes -> consecutive cols
            unsigned cc = compc[c];
            if (cc != cr) {
                float s = 0.0f;
#pragma unroll
                for (int k = 0; k < 64; k += 4) {
                    float4 a = *(const float4*)&xr[r][k];
                    float4 bb = *(const float4*)&xc[c][k];
                    float d0 = a.x - bb.x;
                    float d1 = a.y - bb.y;
                    float d2 = a.z - bb.z;
                    float d3 = a.w - bb.w;
                    s = fmaf(d0, d0, s);
                    s = fmaf(d1, d1, s);
                    s = fmaf(d2, d2, s);
                    s = fmaf(d3, d3, s);
                }
                float w = sqrtf(fmaxf(s, 1e-12f));
                unsigned long long key =
                    ((unsigned long long)__float_as_uint(w) << 24) |
                    ((unsigned long long)(unsigned)rowv << 12) |
                    (unsigned)(tile * 64 + c);
                mykey = key < mykey ? key : mykey;
            }
        }
        __syncthreads();
    }
    keybuf[t] = mykey;
    __syncthreads();
    if (t < 16) {
        unsigned long long k = ~0ULL;
#pragma unroll
        for (int i = 0; i < 16; ++i) {
            unsigned long long v2 = keybuf[t * 16 + i];
            k = v2 < k ? v2 : k;
        }
        if (k != ~0ULL) atomicMin(&best[compr[t]], k);
    }
}

// ---------------------------------------------------------------------------
__global__ __launch_bounds__(256) void merge_kernel(unsigned* comp,
                                                    unsigned long long* best,
                                                    unsigned long long* edges,
                                                    unsigned* nedges, unsigned* done) {
    if (*done) return;
    __shared__ unsigned cl[N];
    __shared__ unsigned np[N];
    __shared__ unsigned cnt;
    const int t = threadIdx.x;
    for (int v = t; v < N; v += 256) cl[v] = comp[v];
    __syncthreads();
    for (int v = t; v < N; v += 256) {
        unsigned p;
        if (cl[v] == (unsigned)v) {
            unsigned long long k = best[v];
            p = (k != ~0ULL) ? cl[(unsigned)(k & 0xFFFu)] : (unsigned)v;
        } else {
            p = cl[v];
        }
        np[v] = p;
    }
    __syncthreads();
    for (int v = t; v < N; v += 256) {
        if (cl[v] == (unsigned)v) {
            unsigned p = np[v];
            if (p != (unsigned)v) {
                bool mutual = (np[p] == (unsigned)v);
                if (mutual && (unsigned)v < p) {
                    np[v] = (unsigned)v;
                } else {
                    unsigned idx = atomicAdd(nedges, 1u);
                    edges[idx] = best[v];
                }
            }
        }
    }
    __syncthreads();
    for (int it = 0; it < 12; ++it) {
        for (int v = t; v < N; v += 256) np[v] = np[np[v]];
        __syncthreads();
    }
    if (t == 0) cnt = 0;
    __syncthreads();
    unsigned local = 0;
    for (int v = t; v < N; v += 256) {
        comp[v] = np[v];
        best[v] = ~0ULL;
        if (np[v] == (unsigned)v) ++local;
    }
    atomicAdd(&cnt, local);
    __syncthreads();
    if (t == 0 && cnt == 1u) *done = 1u;
}

// ---------------------------------------------------------------------------
// Replay without Prim: BFS-root, sort keys, serial DSU chain-merge,
// pointer-doubling position sum, scatter deaths.
// ---------------------------------------------------------------------------
__global__ __launch_bounds__(256) void replay_kernel(
        const unsigned long long* __restrict__ edges,
        const unsigned* __restrict__ nedges, float* __restrict__ out) {
    __shared__ __align__(16) unsigned char pool[132096];
    __shared__ unsigned chg;
    // Phase A (CSR + BFS):
    unsigned* off = (unsigned*)(pool + 0);                          // [4097]
    unsigned long long* ent = (unsigned long long*)(pool + 16392);  // [8190]
    unsigned short* par = (unsigned short*)(pool + 81912);          // [4096]
    unsigned* key = (unsigned*)(pool + 90104);                      // [4096]
    // Phase B (sort + merge + rank); overlays dead phase-A regions:
    unsigned long long* order = (unsigned long long*)(pool + 0);    // [4096]
    unsigned* dsu = (unsigned*)(pool + 32768);                      // [4096]
    unsigned* len = (unsigned*)(pool + 49152);                      // [4096]
    unsigned* vA = (unsigned*)(pool + 65536);                       // [4096]
    unsigned* jA = (unsigned*)(pool + 81920);                       // [4096]
    unsigned* vB = (unsigned*)(pool + 98304);                       // [4096]
    unsigned* jB = (unsigned*)(pool + 114688);                      // [4096]
    unsigned* csum = (unsigned*)(pool + 131072);                    // [256]
    const int t = threadIdx.x;
    const unsigned ne = *nedges;

    // ---- counts ----
    for (int v = t; v < N; v += 256) off[v] = 0u;
    if (t == 0) off[N] = 0u;
    for (int k = t; k < N - 1; k += 256) out[2 * k] = 0.0f;  // births
    __syncthreads();
    for (int e = t; e < (int)ne; e += 256) {
        unsigned long long k = edges[e];
        atomicAdd(&off[(unsigned)(k >> 12) & 0xFFFu], 1u);
        atomicAdd(&off[(unsigned)k & 0xFFFu], 1u);
    }
    __syncthreads();
    // ---- exclusive prefix sum; key[] doubles as insertion pointers ----
    {
        unsigned s = 0;
        int base = t * 16;
        unsigned loc[16];
#pragma unroll
        for (int i = 0; i < 16; ++i) {
            unsigned d = off[base + i];
            loc[i] = s;
            s += d;
        }
        csum[t] = s;
        __syncthreads();
        if (t == 0) {
            unsigned run = 0;
            for (int i = 0; i < 256; ++i) {
                unsigned v2 = csum[i];
                csum[i] = run;
                run += v2;
            }
            off[N] = run;
        }
        __syncthreads();
        unsigned add = csum[t];
#pragma unroll
        for (int i = 0; i < 16; ++i) {
            unsigned o = loc[i] + add;
            off[base + i] = o;
            key[base + i] = o;
        }
    }
    __syncthreads();
    // ---- fill CSR: ent = (wbits<<12)|nbr ----
    for (int e = t; e < (int)ne; e += 256) {
        unsigned long long k = edges[e];
        unsigned a = (unsigned)(k >> 12) & 0xFFFu;
        unsigned b = (unsigned)k & 0xFFFu;
        unsigned long long wb = k >> 24;
        unsigned p1 = atomicAdd(&key[a], 1u);
        ent[p1] = (wb << 12) | b;
        unsigned p2 = atomicAdd(&key[b], 1u);
        ent[p2] = (wb << 12) | a;
    }
    __syncthreads();
    // ---- BFS rooting from 0: key[v]=parent-edge wbits, par[v]=parent ----
    for (int v = t; v < N; v += 256) key[v] = 0xFFFFFFFFu;
    __syncthreads();
    if (t == 0) {
        key[0] = 0u;  // visited marker (wbits are never 0)
        par[0] = 0;
    }
    __syncthreads();
    for (;;) {
        if (t == 0) chg = 0u;
        __syncthreads();
        for (int v = t; v < N; v += 256) {
            if (key[v] == 0xFFFFFFFFu) {
                unsigned o = off[v], oe = off[v + 1];
                for (unsigned e = o; e < oe; ++e) {
                    unsigned long long en = ent[e];
                    unsigned nb = (unsigned)en & 0xFFFu;
                    if (key[nb] != 0xFFFFFFFFu) {
                        // tree: at most one visited neighbor -> deterministic
                        par[v] = (unsigned short)nb;
                        key[v] = (unsigned)(en >> 12);
                        chg = 1u;
                        break;
                    }
                }
            }
        }
        __syncthreads();
        if (chg == 0u) break;
    }
    // ---- fill sort array: (wbits<<24)|(par<<12)|v ; v=0 pads last ----
    for (int v = t; v < N; v += 256) {
        order[v] = (v == 0)
                       ? ~0ULL
                       : (((unsigned long long)key[v]) << 24) |
                             ((unsigned long long)par[v] << 12) | (unsigned)v;
    }
    __syncthreads();
    // ---- bitonic sort ascending (4096 u64) ----
    for (unsigned k = 2; k <= 4096; k <<= 1) {
        for (unsigned j = k >> 1; j > 0; j >>= 1) {
            for (unsigned i = t; i < 4096; i += 256) {
                unsigned p = i ^ j;
                if (p > i) {
                    unsigned long long a = order[i], b = order[p];
                    bool up = ((i & k) == 0);
                    if ((a > b) == up) {
                        order[i] = b;
                        order[p] = a;
                    }
                }
            }
            __syncthreads();
        }
    }
    // ---- phase B init ----
    for (int v = t; v < N; v += 256) {
        dsu[v] = (unsigned)v;
        len[v] = 1u;
        vA[v] = 0u;
        jA[v] = 0u;
    }
    __syncthreads();
    // ---- serial DSU chain-merge (the only serial part; O(1) LDS ops) ----
    if (t == 0) {
        unsigned long long cur = order[0];
#pragma unroll 1
        for (int i = 0; i < N - 1; ++i) {
            unsigned long long nx = order[i + 1];  // prefetch (pad at i=4094)
            unsigned v = (unsigned)cur & 0xFFFu;
            unsigned p = (unsigned)(cur >> 12) & 0xFFFu;
            unsigned x = p;
            for (;;) {  // find with path-halving
                unsigned px = dsu[x];
                if (px == x) break;
                unsigned g = dsu[px];
                if (g == px) { x = px; break; }
                dsu[x] = g;
                x = g;
            }
            unsigned r = x;
            unsigned lr = len[r], lv = len[v];
            vA[v] = lr;       // offset of v's chain inside r's chain
            jA[v] = r;        // merge-tree parent
            len[r] = lr + lv;
            dsu[v] = r;
            cur = nx;
        }
    }
    __syncthreads();
    // ---- pointer-doubling: pos(v) = sum of vA along jA path to 0 ----
    {
        unsigned *va = vA, *vb = vB, *ja = jA, *jb = jB;
        for (int r = 0; r < 12; ++r) {
            for (int v = t; v < N; v += 256) {
                unsigned j2 = ja[v];
                vb[v] = va[v] + va[j2];
                jb[v] = ja[j2];
            }
            __syncthreads();
            unsigned* tmp;
            tmp = va; va = vb; vb = tmp;
            tmp = ja; ja = jb; jb = tmp;
        }
        // ---- scatter deaths: s-th popped vertex -> out[2*(s-1)+1] ----
        for (int i = t; i < N - 1; i += 256) {
            unsigned long long e = order[i];
            unsigned v = (unsigned)e & 0xFFFu;
            unsigned wb = (unsigned)(e >> 24);
            unsigned s = va[v];
            out[2 * (s - 1) + 1] = __uint_as_float(wb);
        }
    }
}

// ---------------------------------------------------------------------------
extern "C" void kernel_launch(void* const* d_in, const int* in_sizes, int n_in,
                              void* d_out, int out_size, void* d_ws, size_t ws_size,
                              hipStream_t stream) {
    const float* x = (const float*)d_in[0];
    unsigned char* ws = (unsigned char*)d_ws;
    unsigned* comp = (unsigned*)ws;                                  // 16 KB
    unsigned long long* best = (unsigned long long*)(ws + 16384);    // 32 KB
    unsigned long long* edges = (unsigned long long*)(ws + 49152);   // 32 KB
    unsigned* nedges = (unsigned*)(ws + 81920);
    unsigned* done = (unsigned*)(ws + 81984);
    float* out = (float*)d_out;  // [N-1][2]: (birth=0, death)

    init_kernel<<<16, 256, 0, stream>>>(comp, best, nedges, done);
    for (int r = 0; r < 12; ++r) {
        minedge_kernel<<<256, 256, 0, stream>>>(x, comp, best, done);
        merge_kernel<<<1, 256, 0, stream>>>(comp, best, edges, nedges, done);
    }
    replay_kernel<<<1, 256, 0, stream>>>(edges, nedges, out);
}

// Round 12
// 1802.456 us; speedup vs baseline: 2.7039x; 1.2538x over previous
//
#include <hip/hip_runtime.h>
#include <math.h>

// RipsLayer: dim-0 persistence of Rips filtration on 4096 points in R^64.
// Boruvka MST (all CUs) + Prim-order-without-Prim replay.
// R11: the serial DSU chain-merge's find(parent) is replaced by a PARALLEL
// ANSV (nearest ancestor with larger key) via monotone pointer jumping:
//   find(parent(v)) at v's pop time == nearest ancestor a with key(a)>key(v)
//   (all smaller-key ancestors already merged upward). In-place jumping
//   ptr[v] <- ptr[ptr[v]] while key(ptr[v]) <= key(v) is safe under any
//   interleaving (skipped vertices provably have key <= key(v)) and
//   converges in O(log N) rounds. The serial loop is then find-free:
//   vA[v]=len[r]; jA[v]=r; len[r]+=len[v]  (r baked into the sort key).
// R10 (passed, absmax 0) validated the merge-tree/preorder theory; only
// ANSV is new. Boruvka phase unchanged.
// (Resubmitted unchanged: R11 bench failed with GPUAcquisitionTimeout —
//  infrastructure, not kernel.)

#define N 4096
#define DF 64
#define INF __builtin_huge_valf()

// ---------------------------------------------------------------------------
__global__ __launch_bounds__(256) void init_kernel(unsigned* comp,
                                                   unsigned long long* best,
                                                   unsigned* nedges, unsigned* done) {
    int i = blockIdx.x * 256 + threadIdx.x;
    if (i < N) {
        comp[i] = (unsigned)i;
        best[i] = ~0ULL;
    }
    if (i == 0) { *nedges = 0u; *done = 0u; }
}

// ---------------------------------------------------------------------------
// Boruvka min-edge: block b scans rows [16b,16b+16) x all 4096 cols.
// Exact build_d fmaf sequence -> w bitwise-identical to reference deaths.
// key = (wbits<<24)|(row<<12)|col.
// ---------------------------------------------------------------------------
__global__ __launch_bounds__(256) void minedge_kernel(const float* __restrict__ x,
                                                      const unsigned* __restrict__ comp,
                                                      unsigned long long* __restrict__ best,
                                                      const unsigned* __restrict__ done) {
    if (*done) return;
    __shared__ float xr[16][64];
    __shared__ float xc[64][68];
    __shared__ unsigned compr[16];
    __shared__ unsigned compc[64];
    __shared__ unsigned long long keybuf[256];
    const int t = threadIdx.x;
    const int b = blockIdx.x;
    const int r = t >> 4;
    const int rowv = b * 16 + r;

    {
        int row = t >> 4, f4 = t & 15;
        *(float4*)&xr[row][f4 * 4] =
            *(const float4*)(x + (size_t)(b * 16 + row) * DF + f4 * 4);
        if (t < 16) compr[t] = comp[b * 16 + t];
    }
    __syncthreads();
    const unsigned cr = compr[r];
    unsigned long long mykey = ~0ULL;

    for (int tile = 0; tile < 64; ++tile) {
        {
#pragma unroll
            for (int q = 0; q < 4; ++q) {
                int idx = t + 256 * q;
                int col = idx >> 4, k4 = (idx & 15) * 4;
                *(float4*)&xc[col][k4] =
                    *(const float4*)(x + (size_t)(tile * 64 + col) * DF + k4);
            }
            if (t < 64) compc[t] = comp[tile * 64 + t];
        }
        __syncthreads();
#pragma unroll
        for (int q = 0; q < 4; ++q) {
            int c = (t & 15) + 16 * q;  // consecutive lanes -> consecutive cols
            unsigned cc = compc[c];
            if (cc != cr) {
                float s = 0.0f;
#pragma unroll
                for (int k = 0; k < 64; k += 4) {
                    float4 a = *(const float4*)&xr[r][k];
                    float4 bb = *(const float4*)&xc[c][k];
                    float d0 = a.x - bb.x;
                    float d1 = a.y - bb.y;
                    float d2 = a.z - bb.z;
                    float d3 = a.w - bb.w;
                    s = fmaf(d0, d0, s);
                    s = fmaf(d1, d1, s);
                    s = fmaf(d2, d2, s);
                    s = fmaf(d3, d3, s);
                }
                float w = sqrtf(fmaxf(s, 1e-12f));
                unsigned long long key =
                    ((unsigned long long)__float_as_uint(w) << 24) |
                    ((unsigned long long)(unsigned)rowv << 12) |
                    (unsigned)(tile * 64 + c);
                mykey = key < mykey ? key : mykey;
            }
        }
        __syncthreads();
    }
    keybuf[t] = mykey;
    __syncthreads();
    if (t < 16) {
        unsigned long long k = ~0ULL;
#pragma unroll
        for (int i = 0; i < 16; ++i) {
            unsigned long long v2 = keybuf[t * 16 + i];
            k = v2 < k ? v2 : k;
        }
        if (k != ~0ULL) atomicMin(&best[compr[t]], k);
    }
}

// ---------------------------------------------------------------------------
__global__ __launch_bounds__(256) void merge_kernel(unsigned* comp,
                                                    unsigned long long* best,
                                                    unsigned long long* edges,
                                                    unsigned* nedges, unsigned* done) {
    if (*done) return;
    __shared__ unsigned cl[N];
    __shared__ unsigned np[N];
    __shared__ unsigned cnt;
    const int t = threadIdx.x;
    for (int v = t; v < N; v += 256) cl[v] = comp[v];
    __syncthreads();
    for (int v = t; v < N; v += 256) {
        unsigned p;
        if (cl[v] == (unsigned)v) {
            unsigned long long k = best[v];
            p = (k != ~0ULL) ? cl[(unsigned)(k & 0xFFFu)] : (unsigned)v;
        } else {
            p = cl[v];
        }
        np[v] = p;
    }
    __syncthreads();
    for (int v = t; v < N; v += 256) {
        if (cl[v] == (unsigned)v) {
            unsigned p = np[v];
            if (p != (unsigned)v) {
                bool mutual = (np[p] == (unsigned)v);
                if (mutual && (unsigned)v < p) {
                    np[v] = (unsigned)v;
                } else {
                    unsigned idx = atomicAdd(nedges, 1u);
                    edges[idx] = best[v];
                }
            }
        }
    }
    __syncthreads();
    for (int it = 0; it < 12; ++it) {
        for (int v = t; v < N; v += 256) np[v] = np[np[v]];
        __syncthreads();
    }
    if (t == 0) cnt = 0;
    __syncthreads();
    unsigned local = 0;
    for (int v = t; v < N; v += 256) {
        comp[v] = np[v];
        best[v] = ~0ULL;
        if (np[v] == (unsigned)v) ++local;
    }
    atomicAdd(&cnt, local);
    __syncthreads();
    if (t == 0 && cnt == 1u) *done = 1u;
}

// ---------------------------------------------------------------------------
// Replay: CSR + BFS rooting -> ANSV (parallel) -> sort -> find-free serial
// chain-merge -> pointer-doubling rank -> scatter.
// ---------------------------------------------------------------------------
__global__ __launch_bounds__(256) void replay_kernel(
        const unsigned long long* __restrict__ edges,
        const unsigned* __restrict__ nedges, float* __restrict__ out) {
    __shared__ __align__(16) unsigned char pool[140296];
    __shared__ unsigned chg;
    // Region map (liveness-checked overlays):
    //  [0,65520)       ent u64[8190]      (CSR; dead after BFS)
    //    [0,32768)       key64 u64[4096]  (ANSV; dead after ANSV)
    //    [0,32768)       order u64[4096]  (built after ANSV; live to end)
    //    [32768,49152)   ptr u32[4096]    (ANSV r; dead after order build)
    //    [32768,49152)   vB u32[4096]     (doubling)
    //  [65536,81928)   off u32[4097]      (CSR/BFS; dead after BFS)
    //    [65536,81920)   len u32[4096]    (serial)
    //  [81928,90120)   par u16[4096]      (dead after key64 fill)
    //  [90120,106504)  keyw u32[4096]     (dead after order build)
    //    [90120,106504)  jB u32[4096]     (doubling)
    //  [106504,107528) csum u32[256]
    //  [107528,123912) vA u32[4096]
    //  [123912,140296) jA u32[4096]
    unsigned* off = (unsigned*)(pool + 65536);
    unsigned long long* ent = (unsigned long long*)(pool + 0);
    unsigned short* par = (unsigned short*)(pool + 81928);
    unsigned* keyw = (unsigned*)(pool + 90120);
    unsigned long long* key64 = (unsigned long long*)(pool + 0);
    unsigned* ptr = (unsigned*)(pool + 32768);
    unsigned long long* order = (unsigned long long*)(pool + 0);
    unsigned* len = (unsigned*)(pool + 65536);
    unsigned* vA = (unsigned*)(pool + 107528);
    unsigned* jA = (unsigned*)(pool + 123912);
    unsigned* vB = (unsigned*)(pool + 32768);
    unsigned* jB = (unsigned*)(pool + 90120);
    unsigned* csum = (unsigned*)(pool + 106504);
    const int t = threadIdx.x;
    const unsigned ne = *nedges;

    // ---- CSR counts ----
    for (int v = t; v < N; v += 256) off[v] = 0u;
    if (t == 0) off[N] = 0u;
    for (int k = t; k < N - 1; k += 256) out[2 * k] = 0.0f;  // births
    __syncthreads();
    for (int e = t; e < (int)ne; e += 256) {
        unsigned long long k = edges[e];
        atomicAdd(&off[(unsigned)(k >> 12) & 0xFFFu], 1u);
        atomicAdd(&off[(unsigned)k & 0xFFFu], 1u);
    }
    __syncthreads();
    // ---- exclusive prefix sum; keyw doubles as insertion pointers ----
    {
        unsigned s = 0;
        int base = t * 16;
        unsigned loc[16];
#pragma unroll
        for (int i = 0; i < 16; ++i) {
            unsigned d = off[base + i];
            loc[i] = s;
            s += d;
        }
        csum[t] = s;
        __syncthreads();
        if (t == 0) {
            unsigned run = 0;
            for (int i = 0; i < 256; ++i) {
                unsigned v2 = csum[i];
                csum[i] = run;
                run += v2;
            }
            off[N] = run;
        }
        __syncthreads();
        unsigned add = csum[t];
#pragma unroll
        for (int i = 0; i < 16; ++i) {
            unsigned o = loc[i] + add;
            off[base + i] = o;
            keyw[base + i] = o;
        }
    }
    __syncthreads();
    // ---- fill CSR: ent = (wbits<<12)|nbr ----
    for (int e = t; e < (int)ne; e += 256) {
        unsigned long long k = edges[e];
        unsigned a = (unsigned)(k >> 12) & 0xFFFu;
        unsigned b = (unsigned)k & 0xFFFu;
        unsigned long long wb = k >> 24;
        unsigned p1 = atomicAdd(&keyw[a], 1u);
        ent[p1] = (wb << 12) | b;
        unsigned p2 = atomicAdd(&keyw[b], 1u);
        ent[p2] = (wb << 12) | a;
    }
    __syncthreads();
    // ---- BFS rooting from 0: keyw[v]=parent-edge wbits, par[v]=parent ----
    for (int v = t; v < N; v += 256) keyw[v] = 0xFFFFFFFFu;
    __syncthreads();
    if (t == 0) {
        keyw[0] = 0u;  // visited marker (wbits are never 0)
        par[0] = 0;
    }
    __syncthreads();
    for (;;) {
        if (t == 0) chg = 0u;
        __syncthreads();
        for (int v = t; v < N; v += 256) {
            if (keyw[v] == 0xFFFFFFFFu) {
                unsigned o = off[v], oe = off[v + 1];
                for (unsigned e = o; e < oe; ++e) {
                    unsigned long long en = ent[e];
                    unsigned nb = (unsigned)en & 0xFFFu;
                    if (keyw[nb] != 0xFFFFFFFFu) {
                        par[v] = (unsigned short)nb;
                        keyw[v] = (unsigned)(en >> 12);
                        chg = 1u;
                        break;
                    }
                }
            }
        }
        __syncthreads();
        if (chg == 0u) break;
    }
    // ---- ANSV: key64 fill (overwrites ent region; BFS done) ----
    for (int v = t; v < N; v += 256) {
        key64[v] = (v == 0) ? ~0ULL
                            : (((unsigned long long)keyw[v]) << 24) |
                                  ((unsigned long long)par[v] << 12) | (unsigned)v;
        ptr[v] = (v == 0) ? 0u : (unsigned)par[v];
        len[v] = 1u;   // off region dead (BFS done)
        vA[v] = 0u;
        jA[v] = 0u;
    }
    __syncthreads();
    // monotone pointer jumping; in-place is safe (skip-invariant holds
    // under any interleaving); converges in ~log2(N) rounds.
    for (int round = 0; round < 64; ++round) {
        if (t == 0) chg = 0u;
        __syncthreads();
        for (int v = t; v < N; v += 256) {
            unsigned p = ptr[v];
            if (key64[p] <= key64[v]) {
                unsigned q = ptr[p];
                if (q != p) {
                    ptr[v] = q;
                    chg = 1u;
                }
            }
        }
        __syncthreads();
        if (chg == 0u) break;
    }
    // ---- build sort array (overwrites key64): (wbits<<24)|(r<<12)|v ----
    for (int v = t; v < N; v += 256) {
        unsigned rr = ptr[v];
        unsigned wbv = keyw[v];
        order[v] = (v == 0)
                       ? ~0ULL
                       : (((unsigned long long)wbv) << 24) |
                             ((unsigned long long)rr << 12) | (unsigned)v;
    }
    __syncthreads();
    // ---- bitonic sort ascending (4096 u64) ----
    for (unsigned k = 2; k <= 4096; k <<= 1) {
        for (unsigned j = k >> 1; j > 0; j >>= 1) {
            for (unsigned i = t; i < 4096; i += 256) {
                unsigned p = i ^ j;
                if (p > i) {
                    unsigned long long a = order[i], b = order[p];
                    bool up = ((i & k) == 0);
                    if ((a > b) == up) {
                        order[i] = b;
                        order[p] = a;
                    }
                }
            }
            __syncthreads();
        }
    }
    // ---- find-free serial chain-merge (only serial part) ----
    if (t == 0) {
        unsigned long long e0 = order[0];
#pragma unroll 1
        for (int i = 0; i < N - 1; ++i) {
            unsigned long long e1 = order[i + 1];  // sentinel at i=N-2
            unsigned v = (unsigned)e0 & 0xFFFu;
            unsigned r = ((unsigned)e0 >> 12) & 0xFFFu;
            unsigned lr = len[r], lv = len[v];
            vA[v] = lr;
            jA[v] = r;
            len[r] = lr + lv;
            e0 = e1;
        }
    }
    __syncthreads();
    // ---- pointer-doubling: pos(v) = sum of vA along jA path to 0 ----
    {
        unsigned *va = vA, *vb = vB, *ja = jA, *jb = jB;
        for (int r = 0; r < 12; ++r) {
            for (int v = t; v < N; v += 256) {
                unsigned j2 = ja[v];
                vb[v] = va[v] + va[j2];
                jb[v] = ja[j2];
            }
            __syncthreads();
            unsigned* tmp;
            tmp = va; va = vb; vb = tmp;
            tmp = ja; ja = jb; jb = tmp;
        }
        // ---- scatter deaths ----
        for (int i = t; i < N - 1; i += 256) {
            unsigned long long e = order[i];
            unsigned v = (unsigned)e & 0xFFFu;
            unsigned wb = (unsigned)(e >> 24);
            unsigned s = va[v];
            out[2 * (s - 1) + 1] = __uint_as_float(wb);
        }
    }
}

// ---------------------------------------------------------------------------
extern "C" void kernel_launch(void* const* d_in, const int* in_sizes, int n_in,
                              void* d_out, int out_size, void* d_ws, size_t ws_size,
                              hipStream_t stream) {
    const float* x = (const float*)d_in[0];
    unsigned char* ws = (unsigned char*)d_ws;
    unsigned* comp = (unsigned*)ws;                                  // 16 KB
    unsigned long long* best = (unsigned long long*)(ws + 16384);    // 32 KB
    unsigned long long* edges = (unsigned long long*)(ws + 49152);   // 32 KB
    unsigned* nedges = (unsigned*)(ws + 81920);
    unsigned* done = (unsigned*)(ws + 81984);
    float* out = (float*)d_out;  // [N-1][2]: (birth=0, death)

    init_kernel<<<16, 256, 0, stream>>>(comp, best, nedges, done);
    for (int r = 0; r < 12; ++r) {
        minedge_kernel<<<256, 256, 0, stream>>>(x, comp, best, done);
        merge_kernel<<<1, 256, 0, stream>>>(comp, best, edges, nedges, done);
    }
    replay_kernel<<<1, 256, 0, stream>>>(edges, nedges, out);
}

// Round 13
// 1208.394 us; speedup vs baseline: 4.0332x; 1.4916x over previous
//
#include <hip/hip_runtime.h>
#include <math.h>

// RipsLayer: dim-0 persistence of Rips filtration on 4096 points in R^64.
// Boruvka MST (all CUs) + FULLY PARALLEL Prim-order reconstruction (R13):
//   R12 proved: pos(v) = sum of vA along ANSV chain, vA from serial chain-
//   merge. R13 removes the serial loop: len-at-merge(u) == S(u), the
//   subtree size in the ANSV forest T' (all dependents have smaller keys),
//   so vA(v) = 1 + sum of S(u) over earlier-key siblings — a segmented
//   prefix sum over an r-major sort. S computed by ~height(T') rounds of
//   parallel child-sum (height = suffix-maxima count, ~O(log) for random
//   weights, early-exit capped). Replay now 1024 threads; chg-flag loops
//   use a race-free 3-barrier pattern. Boruvka phase unchanged.

#define N 4096
#define DF 64
#define INF __builtin_huge_valf()

// ---------------------------------------------------------------------------
__global__ __launch_bounds__(256) void init_kernel(unsigned* comp,
                                                   unsigned long long* best,
                                                   unsigned* nedges, unsigned* done) {
    int i = blockIdx.x * 256 + threadIdx.x;
    if (i < N) {
        comp[i] = (unsigned)i;
        best[i] = ~0ULL;
    }
    if (i == 0) { *nedges = 0u; *done = 0u; }
}

// ---------------------------------------------------------------------------
// Boruvka min-edge: block b scans rows [16b,16b+16) x all 4096 cols.
// Exact build_d fmaf sequence -> weights bitwise-match reference deaths.
// ---------------------------------------------------------------------------
__global__ __launch_bounds__(256) void minedge_kernel(const float* __restrict__ x,
                                                      const unsigned* __restrict__ comp,
                                                      unsigned long long* __restrict__ best,
                                                      const unsigned* __restrict__ done) {
    if (*done) return;
    __shared__ float xr[16][64];
    __shared__ float xc[64][68];
    __shared__ unsigned compr[16];
    __shared__ unsigned compc[64];
    __shared__ unsigned long long keybuf[256];
    const int t = threadIdx.x;
    const int b = blockIdx.x;
    const int r = t >> 4;
    const int rowv = b * 16 + r;

    {
        int row = t >> 4, f4 = t & 15;
        *(float4*)&xr[row][f4 * 4] =
            *(const float4*)(x + (size_t)(b * 16 + row) * DF + f4 * 4);
        if (t < 16) compr[t] = comp[b * 16 + t];
    }
    __syncthreads();
    const unsigned cr = compr[r];
    unsigned long long mykey = ~0ULL;

    for (int tile = 0; tile < 64; ++tile) {
        {
#pragma unroll
            for (int q = 0; q < 4; ++q) {
                int idx = t + 256 * q;
                int col = idx >> 4, k4 = (idx & 15) * 4;
                *(float4*)&xc[col][k4] =
                    *(const float4*)(x + (size_t)(tile * 64 + col) * DF + k4);
            }
            if (t < 64) compc[t] = comp[tile * 64 + t];
        }
        __syncthreads();
#pragma unroll
        for (int q = 0; q < 4; ++q) {
            int c = (t & 15) + 16 * q;
            unsigned cc = compc[c];
            if (cc != cr) {
                float s = 0.0f;
#pragma unroll
                for (int k = 0; k < 64; k += 4) {
                    float4 a = *(const float4*)&xr[r][k];
                    float4 bb = *(const float4*)&xc[c][k];
                    float d0 = a.x - bb.x;
                    float d1 = a.y - bb.y;
                    float d2 = a.z - bb.z;
                    float d3 = a.w - bb.w;
                    s = fmaf(d0, d0, s);
                    s = fmaf(d1, d1, s);
                    s = fmaf(d2, d2, s);
                    s = fmaf(d3, d3, s);
                }
                float w = sqrtf(fmaxf(s, 1e-12f));
                unsigned long long key =
                    ((unsigned long long)__float_as_uint(w) << 24) |
                    ((unsigned long long)(unsigned)rowv << 12) |
                    (unsigned)(tile * 64 + c);
                mykey = key < mykey ? key : mykey;
            }
        }
        __syncthreads();
    }
    keybuf[t] = mykey;
    __syncthreads();
    if (t < 16) {
        unsigned long long k = ~0ULL;
#pragma unroll
        for (int i = 0; i < 16; ++i) {
            unsigned long long v2 = keybuf[t * 16 + i];
            k = v2 < k ? v2 : k;
        }
        if (k != ~0ULL) atomicMin(&best[compr[t]], k);
    }
}

// ---------------------------------------------------------------------------
__global__ __launch_bounds__(256) void merge_kernel(unsigned* comp,
                                                    unsigned long long* best,
                                                    unsigned long long* edges,
                                                    unsigned* nedges, unsigned* done) {
    if (*done) return;
    __shared__ unsigned cl[N];
    __shared__ unsigned np[N];
    __shared__ unsigned cnt;
    const int t = threadIdx.x;
    for (int v = t; v < N; v += 256) cl[v] = comp[v];
    __syncthreads();
    for (int v = t; v < N; v += 256) {
        unsigned p;
        if (cl[v] == (unsigned)v) {
            unsigned long long k = best[v];
            p = (k != ~0ULL) ? cl[(unsigned)(k & 0xFFFu)] : (unsigned)v;
        } else {
            p = cl[v];
        }
        np[v] = p;
    }
    __syncthreads();
    for (int v = t; v < N; v += 256) {
        if (cl[v] == (unsigned)v) {
            unsigned p = np[v];
            if (p != (unsigned)v) {
                bool mutual = (np[p] == (unsigned)v);
                if (mutual && (unsigned)v < p) {
                    np[v] = (unsigned)v;
                } else {
                    unsigned idx = atomicAdd(nedges, 1u);
                    edges[idx] = best[v];
                }
            }
        }
    }
    __syncthreads();
    for (int it = 0; it < 12; ++it) {
        for (int v = t; v < N; v += 256) np[v] = np[np[v]];
        __syncthreads();
    }
    if (t == 0) cnt = 0;
    __syncthreads();
    unsigned local = 0;
    for (int v = t; v < N; v += 256) {
        comp[v] = np[v];
        best[v] = ~0ULL;
        if (np[v] == (unsigned)v) ++local;
    }
    atomicAdd(&cnt, local);
    __syncthreads();
    if (t == 0 && cnt == 1u) *done = 1u;
}

// ---------------------------------------------------------------------------
// Replay (1024 threads): CSR + BFS rooting -> ANSV -> S (child-sum rounds)
// -> r-major sort -> segmented scan (vA) -> pointer-doubling pos -> scatter.
// ---------------------------------------------------------------------------
__global__ __launch_bounds__(1024) void replay_kernel(
        const unsigned long long* __restrict__ edges,
        const unsigned* __restrict__ nedges, float* __restrict__ out) {
    __shared__ __align__(16) unsigned char pool[156680];
    __shared__ unsigned chg;
    // Overlay map (live ranges disjoint):
    //  [0,65520)       ent u64[8190]          (CSR; dead after BFS)
    //    [0,32768)       key64 u64[4096]      (ANSV; dead after ANSV)
    //    [0,32768)       order u64[4096]      (dead after vA extraction)
    //    [0,16384)       vB u32[4096]         (doubling)
    //    [16384,32768)   jB u32[4096]         (doubling)
    //    [32768,49152)   Sa u32[4096]         (S iteration, after BFS)
    //    [49152,65536)   Sb u32[4096]
    //  [65536,81924)   off u32[4097]          (dead after BFS)
    //    [65536,81920)   T u32[4096]          (segscan)
    //  [81928,90120)   par u16[4096]
    //  [90120,106504)  keyw u32[4096]         (wbits; live to scatter)
    //  [106504,122888) ptr u32[4096]          (ANSV r; live to jA fill)
    //  [122888,139272) vA u32[4096]
    //  [139272,155656) jA u32[4096]
    //  [155656,156680) csum u32[256]
    unsigned* off = (unsigned*)(pool + 65536);
    unsigned long long* ent = (unsigned long long*)(pool + 0);
    unsigned short* par = (unsigned short*)(pool + 81928);
    unsigned* keyw = (unsigned*)(pool + 90120);
    unsigned long long* key64 = (unsigned long long*)(pool + 0);
    unsigned long long* order = (unsigned long long*)(pool + 0);
    unsigned* ptr = (unsigned*)(pool + 106504);
    unsigned* Sa = (unsigned*)(pool + 32768);
    unsigned* Sb = (unsigned*)(pool + 49152);
    unsigned* T = (unsigned*)(pool + 65536);
    unsigned* vA = (unsigned*)(pool + 122888);
    unsigned* jA = (unsigned*)(pool + 139272);
    unsigned* vB = (unsigned*)(pool + 0);
    unsigned* jB = (unsigned*)(pool + 16384);
    unsigned* csum = (unsigned*)(pool + 155656);
    const int t = threadIdx.x;  // 0..1023
    const unsigned ne = *nedges;

    // ---- CSR counts ----
    for (int v = t; v < N; v += 1024) off[v] = 0u;
    if (t == 0) off[N] = 0u;
    for (int k = t; k < N - 1; k += 1024) out[2 * k] = 0.0f;  // births
    __syncthreads();
    for (int e = t; e < (int)ne; e += 1024) {
        unsigned long long k = edges[e];
        atomicAdd(&off[(unsigned)(k >> 12) & 0xFFFu], 1u);
        atomicAdd(&off[(unsigned)k & 0xFFFu], 1u);
    }
    __syncthreads();
    // ---- exclusive prefix sum (threads 0..255, 16 slots each) ----
    unsigned sloc = 0;
    unsigned loc[16];
    if (t < 256) {
        int base = t * 16;
#pragma unroll
        for (int i = 0; i < 16; ++i) {
            unsigned d = off[base + i];
            loc[i] = sloc;
            sloc += d;
        }
        csum[t] = sloc;
    }
    __syncthreads();
    for (int d = 1; d < 256; d <<= 1) {  // Hillis-Steele inclusive scan
        unsigned addv = 0;
        if (t < 256 && t >= d) addv = csum[t - d];
        __syncthreads();
        if (t < 256) csum[t] += addv;
        __syncthreads();
    }
    if (t < 256) {
        int base = t * 16;
        unsigned excl = csum[t] - sloc;
#pragma unroll
        for (int i = 0; i < 16; ++i) {
            unsigned o = loc[i] + excl;
            off[base + i] = o;
            keyw[base + i] = o;  // insertion pointers
        }
        if (t == 255) off[N] = csum[255];
    }
    __syncthreads();
    // ---- fill CSR: ent = (wbits<<12)|nbr ----
    for (int e = t; e < (int)ne; e += 1024) {
        unsigned long long k = edges[e];
        unsigned a = (unsigned)(k >> 12) & 0xFFFu;
        unsigned b = (unsigned)k & 0xFFFu;
        unsigned long long wb = k >> 24;
        unsigned p1 = atomicAdd(&keyw[a], 1u);
        ent[p1] = (wb << 12) | b;
        unsigned p2 = atomicAdd(&keyw[b], 1u);
        ent[p2] = (wb << 12) | a;
    }
    __syncthreads();
    // ---- BFS rooting from 0 ----
    for (int v = t; v < N; v += 1024) keyw[v] = 0xFFFFFFFFu;
    __syncthreads();
    if (t == 0) {
        keyw[0] = 0u;  // visited (wbits never 0)
        par[0] = 0;
        chg = 0u;
    }
    __syncthreads();
    for (;;) {
        for (int v = t; v < N; v += 1024) {
            if (keyw[v] == 0xFFFFFFFFu) {
                unsigned o = off[v], oe = off[v + 1];
                for (unsigned e = o; e < oe; ++e) {
                    unsigned long long en = ent[e];
                    unsigned nb = (unsigned)en & 0xFFFu;
                    if (keyw[nb] != 0xFFFFFFFFu) {
                        par[v] = (unsigned short)nb;
                        keyw[v] = (unsigned)(en >> 12);
                        chg = 1u;
                        break;
                    }
                }
            }
        }
        __syncthreads();
        unsigned fin = (chg == 0u);
        __syncthreads();  // all have read chg before reset
        if (t == 0) chg = 0u;
        __syncthreads();
        if (fin) break;
    }
    // ---- ANSV: key64 fill (ent dead) ----
    for (int v = t; v < N; v += 1024) {
        key64[v] = (v == 0) ? ~0ULL
                            : (((unsigned long long)keyw[v]) << 24) |
                                  ((unsigned long long)par[v] << 12) | (unsigned)v;
        ptr[v] = (v == 0) ? 0u : (unsigned)par[v];
    }
    __syncthreads();
    for (;;) {
        for (int v = t; v < N; v += 1024) {
            unsigned p = ptr[v];
            if (key64[p] <= key64[v]) {
                unsigned q = ptr[p];
                if (q != p) {
                    ptr[v] = q;
                    chg = 1u;
                }
            }
        }
        __syncthreads();
        unsigned fin = (chg == 0u);
        __syncthreads();
        if (t == 0) chg = 0u;
        __syncthreads();
        if (fin) break;
    }
    // ---- S: subtree sizes of ANSV forest by child-sum iteration ----
    unsigned* Sc = Sa;
    unsigned* Sn = Sb;
    for (int v = t; v < N; v += 1024) Sc[v] = 1u;
    __syncthreads();
    for (int round = 0; round < 64; ++round) {
        for (int v = t; v < N; v += 1024) Sn[v] = 1u;
        __syncthreads();
        for (int v = t; v < N; v += 1024)
            if (v != 0) atomicAdd(&Sn[ptr[v]], Sc[v]);
        __syncthreads();
        for (int v = t; v < N; v += 1024)
            if (Sn[v] != Sc[v]) chg = 1u;
        __syncthreads();
        unsigned fin = (chg == 0u);
        __syncthreads();
        if (t == 0) chg = 0u;
        __syncthreads();
        unsigned* tmp = Sc; Sc = Sn; Sn = tmp;
        if (fin) break;
    }
    // ---- r-major sort key: (r<<44)|(wbits<<12)|v ; v=0 -> huge key ----
    for (int v = t; v < N; v += 1024) {
        order[v] = (v == 0)
                       ? (0xFFFFFull << 44)
                       : (((unsigned long long)ptr[v]) << 44) |
                             (((unsigned long long)keyw[v]) << 12) | (unsigned)v;
    }
    __syncthreads();
    // ---- bitonic sort ascending (4096 u64, 1024 threads) ----
    for (unsigned k = 2; k <= 4096; k <<= 1) {
        for (unsigned j = k >> 1; j > 0; j >>= 1) {
            for (unsigned i = t; i < 4096; i += 1024) {
                unsigned p = i ^ j;
                if (p > i) {
                    unsigned long long a = order[i], b = order[p];
                    bool up = ((i & k) == 0);
                    if ((a > b) == up) {
                        order[i] = b;
                        order[p] = a;
                    }
                }
            }
            __syncthreads();
        }
    }
    // ---- segmented inclusive scan of S over sibling groups ----
    for (int i = t; i < 4096; i += 1024) {
        unsigned vv = (unsigned)order[i] & 0xFFFu;
        T[i] = Sc[vv];  // v=0 slot harmless (own segment)
    }
    __syncthreads();
    for (int d = 1; d < 4096; d <<= 1) {
        unsigned addv[4];
#pragma unroll
        for (int q = 0; q < 4; ++q) {
            int i = t + 1024 * q;
            addv[q] = 0;
            if (i >= d && (order[i] >> 44) == (order[i - d] >> 44)) addv[q] = T[i - d];
        }
        __syncthreads();
#pragma unroll
        for (int q = 0; q < 4; ++q) T[t + 1024 * q] += addv[q];
        __syncthreads();
    }
    // ---- vA extraction: vA(v) = 1 + (segment prefix excluding self) ----
    for (int i = t; i < 4096; i += 1024) {
        unsigned vv = (unsigned)order[i] & 0xFFFu;
        if (vv) {
            vA[vv] = 1u + T[i] - Sc[vv];
            jA[vv] = ptr[vv];
        }
    }
    if (t == 0) {
        vA[0] = 0u;
        jA[0] = 0u;
    }
    __syncthreads();
    // ---- pointer-doubling: pos(v) = sum of vA along jA path ----
    {
        unsigned *va = vA, *vb = vB, *ja = jA, *jb = jB;  // vB/jB overlay order
        for (int r = 0; r < 12; ++r) {
            for (int v = t; v < N; v += 1024) {
                unsigned j2 = ja[v];
                vb[v] = va[v] + va[j2];
                jb[v] = ja[j2];
            }
            __syncthreads();
            unsigned* tmp;
            tmp = va; va = vb; vb = tmp;
            tmp = ja; ja = jb; jb = tmp;
        }
        // ---- scatter deaths ----
        for (int v = t; v < N; v += 1024) {
            if (v) out[2 * (va[v] - 1) + 1] = __uint_as_float(keyw[v]);
        }
    }
}

// ---------------------------------------------------------------------------
extern "C" void kernel_launch(void* const* d_in, const int* in_sizes, int n_in,
                              void* d_out, int out_size, void* d_ws, size_t ws_size,
                              hipStream_t stream) {
    const float* x = (const float*)d_in[0];
    unsigned char* ws = (unsigned char*)d_ws;
    unsigned* comp = (unsigned*)ws;                                  // 16 KB
    unsigned long long* best = (unsigned long long*)(ws + 16384);    // 32 KB
    unsigned long long* edges = (unsigned long long*)(ws + 49152);   // 32 KB
    unsigned* nedges = (unsigned*)(ws + 81920);
    unsigned* done = (unsigned*)(ws + 81984);
    float* out = (float*)d_out;  // [N-1][2]: (birth=0, death)

    init_kernel<<<16, 256, 0, stream>>>(comp, best, nedges, done);
    for (int r = 0; r < 12; ++r) {
        minedge_kernel<<<256, 256, 0, stream>>>(x, comp, best, done);
        merge_kernel<<<1, 256, 0, stream>>>(comp, best, edges, nedges, done);
    }
    replay_kernel<<<1, 1024, 0, stream>>>(edges, nedges, out);
}

// Round 14
// 641.504 us; speedup vs baseline: 7.5973x; 1.8837x over previous
//
#include <hip/hip_runtime.h>
#include <math.h>

// RipsLayer: dim-0 persistence of Rips filtration on 4096 points in R^64.
// R14: Boruvka phase made memory-bound. build_d (verified R0 kernel)
// materializes D (64 MiB, L3-resident) once; minedge rounds become pure
// streaming row-scans over D (was: recompute all 16M distances per round,
// ~75us VALU/LDS-bound -> ~10-20us L3-bound). Keys bitwise identical
// ((wbits<<24)|(row<<12)|col), so edges & replay unchanged. merge -> 1024
// threads. Runtime branch: if ws_size < 64MiB+80KB, fall back to the R13
// recompute path verbatim (no regression possible).
// Replay = R13's fully-parallel reconstruction (BFS root -> ANSV ->
// subtree sizes -> r-major sort -> segmented scan -> doubling), verified.

#define N 4096
#define DF 64
#define INF __builtin_huge_valf()

// ---------------------------------------------------------------------------
// build_d (R0-verified): D[i][j] = sqrt(max(|xi-xj|^2,1e-12)), diag=+inf.
// ---------------------------------------------------------------------------
__global__ __launch_bounds__(256) void build_d_kernel(const float* __restrict__ x,
                                                      float* __restrict__ D) {
    __shared__ float As[64][68];
    __shared__ float Bs[64][68];
    const int bi = blockIdx.y * 64;
    const int bj = blockIdx.x * 64;
    const int t = threadIdx.x;

#pragma unroll
    for (int g = 0; g < 4; ++g) {
        int idx = t + 256 * g;
        int row = idx >> 4;
        int k4 = (idx & 15) << 2;
        float4 va = *(const float4*)(x + (size_t)(bi + row) * DF + k4);
        float4 vb = *(const float4*)(x + (size_t)(bj + row) * DF + k4);
        *(float4*)(&As[row][k4]) = va;
        *(float4*)(&Bs[row][k4]) = vb;
    }
    __syncthreads();

    const int ti = (t >> 4) << 2;
    const int tj = (t & 15) << 2;
    float acc[4][4];
#pragma unroll
    for (int r = 0; r < 4; ++r)
#pragma unroll
        for (int c = 0; c < 4; ++c) acc[r][c] = 0.0f;

    for (int k = 0; k < 64; k += 4) {
        float4 a[4], b[4];
#pragma unroll
        for (int r = 0; r < 4; ++r) a[r] = *(const float4*)(&As[ti + r][k]);
#pragma unroll
        for (int c = 0; c < 4; ++c) b[c] = *(const float4*)(&Bs[tj + c][k]);
#pragma unroll
        for (int r = 0; r < 4; ++r)
#pragma unroll
            for (int c = 0; c < 4; ++c) {
                float d0 = a[r].x - b[c].x;
                float d1 = a[r].y - b[c].y;
                float d2 = a[r].z - b[c].z;
                float d3 = a[r].w - b[c].w;
                float s = acc[r][c];
                s = fmaf(d0, d0, s);
                s = fmaf(d1, d1, s);
                s = fmaf(d2, d2, s);
                s = fmaf(d3, d3, s);
                acc[r][c] = s;
            }
    }
#pragma unroll
    for (int r = 0; r < 4; ++r) {
        int i = bi + ti + r;
        float4 v;
        float* vp = &v.x;
#pragma unroll
        for (int c = 0; c < 4; ++c) {
            int j = bj + tj + c;
            vp[c] = (i == j) ? INF : sqrtf(fmaxf(acc[r][c], 1e-12f));
        }
        *(float4*)(D + (size_t)i * N + (bj + tj)) = v;
    }
}

// ---------------------------------------------------------------------------
__global__ __launch_bounds__(256) void init_kernel(unsigned* comp,
                                                   unsigned long long* best,
                                                   unsigned* nedges, unsigned* done) {
    int i = blockIdx.x * 256 + threadIdx.x;
    if (i < N) {
        comp[i] = (unsigned)i;
        best[i] = ~0ULL;
    }
    if (i == 0) { *nedges = 0u; *done = 0u; }
}

// ---------------------------------------------------------------------------
// Cached-D minedge: block b scans rows [16b,16b+16) x all cols from D.
// Memory-bound streaming; key identical to recompute version.
// ---------------------------------------------------------------------------
__global__ __launch_bounds__(256) void minedge_d_kernel(const float* __restrict__ D,
                                                        const unsigned* __restrict__ comp,
                                                        unsigned long long* __restrict__ best,
                                                        const unsigned* __restrict__ done) {
    if (*done) return;
    __shared__ unsigned compc[N];
    __shared__ unsigned long long keybuf[256];
    const int t = threadIdx.x;
    const int b = blockIdx.x;
    const int r = t >> 4;
    const int j = t & 15;
    const int rowv = b * 16 + r;

    for (int v = t; v < N; v += 256) compc[v] = comp[v];
    __syncthreads();
    const unsigned cr = compc[rowv];
    const float4* rowp = (const float4*)(D + (size_t)rowv * N);
    unsigned long long mykey = ~0ULL;
#pragma unroll 4
    for (int k = 0; k < 64; ++k) {
        float4 v4 = rowp[j + 16 * k];
        int c0 = 4 * (j + 16 * k);
        const float* vp = &v4.x;
#pragma unroll
        for (int q = 0; q < 4; ++q) {
            int c = c0 + q;
            if (compc[c] != cr) {
                unsigned long long key =
                    ((unsigned long long)__float_as_uint(vp[q]) << 24) |
                    ((unsigned long long)(unsigned)rowv << 12) | (unsigned)c;
                mykey = key < mykey ? key : mykey;
            }
        }
    }
    keybuf[t] = mykey;
    __syncthreads();
    if (t < 16) {
        unsigned long long k = ~0ULL;
#pragma unroll
        for (int i = 0; i < 16; ++i) {
            unsigned long long v2 = keybuf[t * 16 + i];
            k = v2 < k ? v2 : k;
        }
        if (k != ~0ULL) atomicMin(&best[compc[b * 16 + t]], k);
    }
}

// ---------------------------------------------------------------------------
// Recompute minedge (R13 fallback path, verified).
// ---------------------------------------------------------------------------
__global__ __launch_bounds__(256) void minedge_kernel(const float* __restrict__ x,
                                                      const unsigned* __restrict__ comp,
                                                      unsigned long long* __restrict__ best,
                                                      const unsigned* __restrict__ done) {
    if (*done) return;
    __shared__ float xr[16][64];
    __shared__ float xc[64][68];
    __shared__ unsigned compr[16];
    __shared__ unsigned compc[64];
    __shared__ unsigned long long keybuf[256];
    const int t = threadIdx.x;
    const int b = blockIdx.x;
    const int r = t >> 4;
    const int rowv = b * 16 + r;

    {
        int row = t >> 4, f4 = t & 15;
        *(float4*)&xr[row][f4 * 4] =
            *(const float4*)(x + (size_t)(b * 16 + row) * DF + f4 * 4);
        if (t < 16) compr[t] = comp[b * 16 + t];
    }
    __syncthreads();
    const unsigned cr = compr[r];
    unsigned long long mykey = ~0ULL;

    for (int tile = 0; tile < 64; ++tile) {
        {
#pragma unroll
            for (int q = 0; q < 4; ++q) {
                int idx = t + 256 * q;
                int col = idx >> 4, k4 = (idx & 15) * 4;
                *(float4*)&xc[col][k4] =
                    *(const float4*)(x + (size_t)(tile * 64 + col) * DF + k4);
            }
            if (t < 64) compc[t] = comp[tile * 64 + t];
        }
        __syncthreads();
#pragma unroll
        for (int q = 0; q < 4; ++q) {
            int c = (t & 15) + 16 * q;
            unsigned cc = compc[c];
            if (cc != cr) {
                float s = 0.0f;
#pragma unroll
                for (int k = 0; k < 64; k += 4) {
                    float4 a = *(const float4*)&xr[r][k];
                    float4 bb = *(const float4*)&xc[c][k];
                    float d0 = a.x - bb.x;
                    float d1 = a.y - bb.y;
                    float d2 = a.z - bb.z;
                    float d3 = a.w - bb.w;
                    s = fmaf(d0, d0, s);
                    s = fmaf(d1, d1, s);
                    s = fmaf(d2, d2, s);
                    s = fmaf(d3, d3, s);
                }
                float w = sqrtf(fmaxf(s, 1e-12f));
                unsigned long long key =
                    ((unsigned long long)__float_as_uint(w) << 24) |
                    ((unsigned long long)(unsigned)rowv << 12) |
                    (unsigned)(tile * 64 + c);
                mykey = key < mykey ? key : mykey;
            }
        }
        __syncthreads();
    }
    keybuf[t] = mykey;
    __syncthreads();
    if (t < 16) {
        unsigned long long k = ~0ULL;
#pragma unroll
        for (int i = 0; i < 16; ++i) {
            unsigned long long v2 = keybuf[t * 16 + i];
            k = v2 < k ? v2 : k;
        }
        if (k != ~0ULL) atomicMin(&best[compr[t]], k);
    }
}

// ---------------------------------------------------------------------------
// Boruvka merge (thread-count agnostic; launched with 1024).
// ---------------------------------------------------------------------------
__global__ void merge_kernel(unsigned* comp, unsigned long long* best,
                             unsigned long long* edges, unsigned* nedges,
                             unsigned* done) {
    if (*done) return;
    __shared__ unsigned cl[N];
    __shared__ unsigned np[N];
    __shared__ unsigned cnt;
    const int t = threadIdx.x;
    const int bs = blockDim.x;
    for (int v = t; v < N; v += bs) cl[v] = comp[v];
    __syncthreads();
    for (int v = t; v < N; v += bs) {
        unsigned p;
        if (cl[v] == (unsigned)v) {
            unsigned long long k = best[v];
            p = (k != ~0ULL) ? cl[(unsigned)(k & 0xFFFu)] : (unsigned)v;
        } else {
            p = cl[v];
        }
        np[v] = p;
    }
    __syncthreads();
    for (int v = t; v < N; v += bs) {
        if (cl[v] == (unsigned)v) {
            unsigned p = np[v];
            if (p != (unsigned)v) {
                bool mutual = (np[p] == (unsigned)v);
                if (mutual && (unsigned)v < p) {
                    np[v] = (unsigned)v;
                } else {
                    unsigned idx = atomicAdd(nedges, 1u);
                    edges[idx] = best[v];
                }
            }
        }
    }
    __syncthreads();
    for (int it = 0; it < 12; ++it) {
        for (int v = t; v < N; v += bs) np[v] = np[np[v]];
        __syncthreads();
    }
    if (t == 0) cnt = 0;
    __syncthreads();
    unsigned local = 0;
    for (int v = t; v < N; v += bs) {
        comp[v] = np[v];
        best[v] = ~0ULL;
        if (np[v] == (unsigned)v) ++local;
    }
    atomicAdd(&cnt, local);
    __syncthreads();
    if (t == 0 && cnt == 1u) *done = 1u;
}

// ---------------------------------------------------------------------------
// Replay (R13, verified): CSR + BFS -> ANSV -> S -> r-major sort ->
// segmented scan -> pointer-doubling -> scatter. 1024 threads.
// ---------------------------------------------------------------------------
__global__ __launch_bounds__(1024) void replay_kernel(
        const unsigned long long* __restrict__ edges,
        const unsigned* __restrict__ nedges, float* __restrict__ out) {
    __shared__ __align__(16) unsigned char pool[156680];
    __shared__ unsigned chg;
    unsigned* off = (unsigned*)(pool + 65536);
    unsigned long long* ent = (unsigned long long*)(pool + 0);
    unsigned short* par = (unsigned short*)(pool + 81928);
    unsigned* keyw = (unsigned*)(pool + 90120);
    unsigned long long* key64 = (unsigned long long*)(pool + 0);
    unsigned long long* order = (unsigned long long*)(pool + 0);
    unsigned* ptr = (unsigned*)(pool + 106504);
    unsigned* Sa = (unsigned*)(pool + 32768);
    unsigned* Sb = (unsigned*)(pool + 49152);
    unsigned* T = (unsigned*)(pool + 65536);
    unsigned* vA = (unsigned*)(pool + 122888);
    unsigned* jA = (unsigned*)(pool + 139272);
    unsigned* vB = (unsigned*)(pool + 0);
    unsigned* jB = (unsigned*)(pool + 16384);
    unsigned* csum = (unsigned*)(pool + 155656);
    const int t = threadIdx.x;
    const unsigned ne = *nedges;

    for (int v = t; v < N; v += 1024) off[v] = 0u;
    if (t == 0) off[N] = 0u;
    for (int k = t; k < N - 1; k += 1024) out[2 * k] = 0.0f;
    __syncthreads();
    for (int e = t; e < (int)ne; e += 1024) {
        unsigned long long k = edges[e];
        atomicAdd(&off[(unsigned)(k >> 12) & 0xFFFu], 1u);
        atomicAdd(&off[(unsigned)k & 0xFFFu], 1u);
    }
    __syncthreads();
    unsigned sloc = 0;
    unsigned loc[16];
    if (t < 256) {
        int base = t * 16;
#pragma unroll
        for (int i = 0; i < 16; ++i) {
            unsigned d = off[base + i];
            loc[i] = sloc;
            sloc += d;
        }
        csum[t] = sloc;
    }
    __syncthreads();
    for (int d = 1; d < 256; d <<= 1) {
        unsigned addv = 0;
        if (t < 256 && t >= d) addv = csum[t - d];
        __syncthreads();
        if (t < 256) csum[t] += addv;
        __syncthreads();
    }
    if (t < 256) {
        int base = t * 16;
        unsigned excl = csum[t] - sloc;
#pragma unroll
        for (int i = 0; i < 16; ++i) {
            unsigned o = loc[i] + excl;
            off[base + i] = o;
            keyw[base + i] = o;
        }
        if (t == 255) off[N] = csum[255];
    }
    __syncthreads();
    for (int e = t; e < (int)ne; e += 1024) {
        unsigned long long k = edges[e];
        unsigned a = (unsigned)(k >> 12) & 0xFFFu;
        unsigned b = (unsigned)k & 0xFFFu;
        unsigned long long wb = k >> 24;
        unsigned p1 = atomicAdd(&keyw[a], 1u);
        ent[p1] = (wb << 12) | b;
        unsigned p2 = atomicAdd(&keyw[b], 1u);
        ent[p2] = (wb << 12) | a;
    }
    __syncthreads();
    for (int v = t; v < N; v += 1024) keyw[v] = 0xFFFFFFFFu;
    __syncthreads();
    if (t == 0) {
        keyw[0] = 0u;
        par[0] = 0;
        chg = 0u;
    }
    __syncthreads();
    for (;;) {
        for (int v = t; v < N; v += 1024) {
            if (keyw[v] == 0xFFFFFFFFu) {
                unsigned o = off[v], oe = off[v + 1];
                for (unsigned e = o; e < oe; ++e) {
                    unsigned long long en = ent[e];
                    unsigned nb = (unsigned)en & 0xFFFu;
                    if (keyw[nb] != 0xFFFFFFFFu) {
                        par[v] = (unsigned short)nb;
                        keyw[v] = (unsigned)(en >> 12);
                        chg = 1u;
                        break;
                    }
                }
            }
        }
        __syncthreads();
        unsigned fin = (chg == 0u);
        __syncthreads();
        if (t == 0) chg = 0u;
        __syncthreads();
        if (fin) break;
    }
    for (int v = t; v < N; v += 1024) {
        key64[v] = (v == 0) ? ~0ULL
                            : (((unsigned long long)keyw[v]) << 24) |
                                  ((unsigned long long)par[v] << 12) | (unsigned)v;
        ptr[v] = (v == 0) ? 0u : (unsigned)par[v];
    }
    __syncthreads();
    for (;;) {
        for (int v = t; v < N; v += 1024) {
            unsigned p = ptr[v];
            if (key64[p] <= key64[v]) {
                unsigned q = ptr[p];
                if (q != p) {
                    ptr[v] = q;
                    chg = 1u;
                }
            }
        }
        __syncthreads();
        unsigned fin = (chg == 0u);
        __syncthreads();
        if (t == 0) chg = 0u;
        __syncthreads();
        if (fin) break;
    }
    unsigned* Sc = Sa;
    unsigned* Sn = Sb;
    for (int v = t; v < N; v += 1024) Sc[v] = 1u;
    __syncthreads();
    for (int round = 0; round < 64; ++round) {
        for (int v = t; v < N; v += 1024) Sn[v] = 1u;
        __syncthreads();
        for (int v = t; v < N; v += 1024)
            if (v != 0) atomicAdd(&Sn[ptr[v]], Sc[v]);
        __syncthreads();
        for (int v = t; v < N; v += 1024)
            if (Sn[v] != Sc[v]) chg = 1u;
        __syncthreads();
        unsigned fin = (chg == 0u);
        __syncthreads();
        if (t == 0) chg = 0u;
        __syncthreads();
        unsigned* tmp = Sc; Sc = Sn; Sn = tmp;
        if (fin) break;
    }
    for (int v = t; v < N; v += 1024) {
        order[v] = (v == 0)
                       ? (0xFFFFFull << 44)
                       : (((unsigned long long)ptr[v]) << 44) |
                             (((unsigned long long)keyw[v]) << 12) | (unsigned)v;
    }
    __syncthreads();
    for (unsigned k = 2; k <= 4096; k <<= 1) {
        for (unsigned j = k >> 1; j > 0; j >>= 1) {
            for (unsigned i = t; i < 4096; i += 1024) {
                unsigned p = i ^ j;
                if (p > i) {
                    unsigned long long a = order[i], b = order[p];
                    bool up = ((i & k) == 0);
                    if ((a > b) == up) {
                        order[i] = b;
                        order[p] = a;
                    }
                }
            }
            __syncthreads();
        }
    }
    for (int i = t; i < 4096; i += 1024) {
        unsigned vv = (unsigned)order[i] & 0xFFFu;
        T[i] = Sc[vv];
    }
    __syncthreads();
    for (int d = 1; d < 4096; d <<= 1) {
        unsigned addv[4];
#pragma unroll
        for (int q = 0; q < 4; ++q) {
            int i = t + 1024 * q;
            addv[q] = 0;
            if (i >= d && (order[i] >> 44) == (order[i - d] >> 44)) addv[q] = T[i - d];
        }
        __syncthreads();
#pragma unroll
        for (int q = 0; q < 4; ++q) T[t + 1024 * q] += addv[q];
        __syncthreads();
    }
    for (int i = t; i < 4096; i += 1024) {
        unsigned vv = (unsigned)order[i] & 0xFFFu;
        if (vv) {
            vA[vv] = 1u + T[i] - Sc[vv];
            jA[vv] = ptr[vv];
        }
    }
    if (t == 0) {
        vA[0] = 0u;
        jA[0] = 0u;
    }
    __syncthreads();
    {
        unsigned *va = vA, *vb = vB, *ja = jA, *jb = jB;
        for (int r = 0; r < 12; ++r) {
            for (int v = t; v < N; v += 1024) {
                unsigned j2 = ja[v];
                vb[v] = va[v] + va[j2];
                jb[v] = ja[j2];
            }
            __syncthreads();
            unsigned* tmp;
            tmp = va; va = vb; vb = tmp;
            tmp = ja; ja = jb; jb = tmp;
        }
        for (int v = t; v < N; v += 1024) {
            if (v) out[2 * (va[v] - 1) + 1] = __uint_as_float(keyw[v]);
        }
    }
}

// ---------------------------------------------------------------------------
extern "C" void kernel_launch(void* const* d_in, const int* in_sizes, int n_in,
                              void* d_out, int out_size, void* d_ws, size_t ws_size,
                              hipStream_t stream) {
    const float* x = (const float*)d_in[0];
    float* out = (float*)d_out;  // [N-1][2]: (birth=0, death)
    const size_t dbytes = (size_t)N * N * 4;

    if (ws_size >= dbytes + 81920) {
        // Cached-D path: D + state after it.
        float* D = (float*)d_ws;
        unsigned char* st = (unsigned char*)d_ws + dbytes;
        unsigned long long* best = (unsigned long long*)st;            // 32 KB
        unsigned* comp = (unsigned*)(st + 32768);                      // 16 KB
        unsigned long long* edges = (unsigned long long*)(st + 49152); // 32760 B
        unsigned* nedges = (unsigned*)(st + 81912);
        unsigned* done = (unsigned*)(st + 81916);

        dim3 grid(N / 64, N / 64);
        build_d_kernel<<<grid, 256, 0, stream>>>(x, D);
        init_kernel<<<16, 256, 0, stream>>>(comp, best, nedges, done);
        for (int r = 0; r < 12; ++r) {
            minedge_d_kernel<<<256, 256, 0, stream>>>(D, comp, best, done);
            merge_kernel<<<1, 1024, 0, stream>>>(comp, best, edges, nedges, done);
        }
        replay_kernel<<<1, 1024, 0, stream>>>(edges, nedges, out);
    } else {
        // R13 fallback: recompute distances each round (fits in 82 KB ws).
        unsigned char* ws = (unsigned char*)d_ws;
        unsigned* comp = (unsigned*)ws;                                  // 16 KB
        unsigned long long* best = (unsigned long long*)(ws + 16384);    // 32 KB
        unsigned long long* edges = (unsigned long long*)(ws + 49152);   // 32 KB
        unsigned* nedges = (unsigned*)(ws + 81920);
        unsigned* done = (unsigned*)(ws + 81984);

        init_kernel<<<16, 256, 0, stream>>>(comp, best, nedges, done);
        for (int r = 0; r < 12; ++r) {
            minedge_kernel<<<256, 256, 0, stream>>>(x, comp, best, done);
            merge_kernel<<<1, 1024, 0, stream>>>(comp, best, edges, nedges, done);
        }
        replay_kernel<<<1, 1024, 0, stream>>>(edges, nedges, out);
    }
}